// Round 3
// baseline (533.742 us; speedup 1.0000x reference)
//
#include <hip/hip_runtime.h>
#include <math.h>

#define NPT 65536
#define NB 4
#define R3 32768

typedef __attribute__((ext_vector_type(8))) short short8;
typedef __attribute__((ext_vector_type(16))) float f32x16;

// ws layout (float offsets)
#define OFF_WB16 0          // 276480 floats = 552960 bf16: 5 conv layers, B-frag order
#define OFF_BEFF 276480     // 5*64 conv biases (BN-folded)
#define OFF_PWB  276800     // 2048 floats = 4096 bf16: point-branch weights, B-frag order
#define OFF_PB   280896     // 64
#define OFF_WAE  280960     // 64
#define OFF_WBE  281024     // 64
#define OFF_Q0   281088     // 1 (+pad)
#define OFF_MEAN 281104     // 12
#define OFF_MAXN 281116     // 4
#define OFF_PART 281120     // 128 reduction partials (96 mean + 32 max)
#define OFF_AUX  281248     // 256 scan block sums (int)
#define OFF_CB3  281504     // 786432: 3 floats/point normalized coords
#define OFF_CUR  1067936    // 131072 int cursor
#define OFF_ORD  1199008    // 131072 floats = 262144 ushort sorted point ids
#define OFF_GA   1330080    // 8388608 fp32 residual; FT bf16 overlays pre-conv; PF bf16 overlays post-conv
#define OFF_G0   9718688    // 4194304 floats = 8388608 bf16 swizzled grid ping
#define OFF_G1   13912992   // 4194304 floats = 8388608 bf16 swizzled grid pong

__device__ __forceinline__ unsigned short f2b(float f) {
    union { float f; unsigned int u; } v; v.f = f;
    unsigned int r = v.u + 0x7fffu + ((v.u >> 16) & 1u);
    return (unsigned short)(r >> 16);
}
__device__ __forceinline__ float b2f(unsigned short u) {
    union { unsigned int u; float f; } v; v.u = ((unsigned int)u) << 16; return v.f;
}

// merged: conv-weight fold (idx < 552960) + misc param prep (idx >= 552960)
// conv weight layout (per layer, shorts): [tap 27][ks 4][nh 2][lane 64][j 8]
__global__ void k_setup(const float* __restrict__ vconv_w, const float* __restrict__ vconv_b,
                        const float* __restrict__ vbn_g, const float* __restrict__ vbn_b,
                        const float* __restrict__ res_w, const float* __restrict__ res_b,
                        const float* __restrict__ res_bn_g, const float* __restrict__ res_bn_b,
                        const float* __restrict__ pf_w, const float* __restrict__ pf_b,
                        const float* __restrict__ pf_bn_g, const float* __restrict__ pf_bn_b,
                        const float* __restrict__ wa, const float* __restrict__ ba,
                        const float* __restrict__ wb, const float* __restrict__ bb,
                        const float* __restrict__ wc, const float* __restrict__ bc,
                        float* __restrict__ ws) {
    int idx = blockIdx.x * 256 + threadIdx.x;
    const float invs = rsqrtf(1.00001f);
    if (idx < 552960) {
        unsigned short* wb16 = (unsigned short*)(ws + OFF_WB16);
        int j = idx & 7;
        int l = (idx >> 3) & 63;
        int nh = (idx >> 9) & 1;
        int ks = (idx >> 10) & 3;
        int rest = idx >> 12;          // layer*27 + t
        int t = rest % 27;
        int layer = rest / 27;
        int i = ks * 16 + ((l >> 5) << 3) + j;
        int o = nh * 32 + (l & 31);
        float scale, wsrc;
        if (layer == 0) {
            scale = vbn_g[o] * invs;
            wsrc = vconv_w[(o * 64 + i) * 27 + t];
        } else {
            scale = res_bn_g[(layer - 1) * 64 + o] * invs;
            wsrc = res_w[(size_t)(layer - 1) * 110592 + (o * 64 + i) * 27 + t];
        }
        wb16[idx] = f2b(wsrc * scale);
        return;
    }
    idx -= 552960;
    if (idx < 320) {
        int l = idx >> 6, o = idx & 63;
        float b_, g_, s_;
        if (l == 0) { b_ = vconv_b[o]; g_ = vbn_g[o]; s_ = vbn_b[o]; }
        else {
            b_ = res_b[(l - 1) * 64 + o];
            g_ = res_bn_g[(l - 1) * 64 + o];
            s_ = res_bn_b[(l - 1) * 64 + o];
        }
        ws[OFF_BEFF + idx] = b_ * g_ * invs + s_;
    } else if (idx < 4416) {
        int e = idx - 320;                 // 0..4095
        int j = e & 7;
        int lane = (e >> 3) & 63;
        int ks = (e >> 9) & 3;
        int half = e >> 11;
        int i = ks * 16 + ((lane >> 5) << 3) + j;
        int o = half * 32 + (lane & 31);
        ((unsigned short*)(ws + OFF_PWB))[e] = f2b(pf_w[o * 64 + i] * pf_bn_g[o] * invs);
    } else if (idx < 4480) {
        int o = idx - 4416;
        ws[OFF_PB + o] = pf_b[o] * pf_bn_g[o] * invs + pf_bn_b[o];
    } else if (idx < 4544) {
        int o = idx - 4480;
        float s = 0.f;
        for (int j = 0; j < 16; j++) s += wc[j] * wa[j * 64 + o];
        ws[OFF_WAE + o] = s;
    } else if (idx < 4608) {
        int o = idx - 4544;
        float s = 0.f;
        for (int j = 0; j < 16; j++) s += wc[16 + j] * wb[j * 64 + o];
        ws[OFF_WBE + o] = s;
    } else if (idx == 4608) {
        float s = bc[0];
        for (int j = 0; j < 16; j++) s += wc[j] * ba[j] + wc[16 + j] * bb[j];
        ws[OFF_Q0] = s;
    }
}

// stage-1 mean partials (96 blocks = 12 (b,d) x 8 chunks) + grid-stride zero of CUR
__global__ __launch_bounds__(256) void k_mean1(const float* __restrict__ coords,
                                               float* __restrict__ part,
                                               float4* __restrict__ curz) {
    for (int i = blockIdx.x * 256 + threadIdx.x; i < 32768; i += 96 * 256)
        curz[i] = make_float4(0.f, 0.f, 0.f, 0.f);
    __shared__ float sm[256];
    int bd = blockIdx.x >> 3, chunk = blockIdx.x & 7;
    int tid = threadIdx.x;
    const float* p = coords + (size_t)bd * NPT + chunk * 8192;
    float s = 0.f;
    for (int n = tid; n < 8192; n += 256) s += p[n];
    sm[tid] = s; __syncthreads();
    for (int st = 128; st > 0; st >>= 1) {
        if (tid < st) sm[tid] += sm[tid + st];
        __syncthreads();
    }
    if (tid == 0) part[blockIdx.x] = sm[0];
}

// stage-1 max-norm^2 partials (32 blocks = 4 b x 8 chunks); mean computed from partials inline.
// chunk-0 block stores mean for k_prep.
__global__ __launch_bounds__(256) void k_maxn1(const float* __restrict__ coords,
                                               float* __restrict__ part,
                                               float* __restrict__ mean) {
    __shared__ float sm[256];
    int b = blockIdx.x >> 3, chunk = blockIdx.x & 7;
    int tid = threadIdx.x;
    float m0 = 0.f, m1 = 0.f, m2 = 0.f;
    #pragma unroll
    for (int c = 0; c < 8; c++) {
        m0 += part[(b * 3 + 0) * 8 + c];
        m1 += part[(b * 3 + 1) * 8 + c];
        m2 += part[(b * 3 + 2) * 8 + c];
    }
    m0 *= (1.0f / NPT); m1 *= (1.0f / NPT); m2 *= (1.0f / NPT);
    if (chunk == 0 && tid == 0) {
        mean[b * 3] = m0; mean[b * 3 + 1] = m1; mean[b * 3 + 2] = m2;
    }
    const float* p0 = coords + (size_t)(b * 3) * NPT + chunk * 8192;
    float mx = 0.f;
    for (int n = tid; n < 8192; n += 256) {
        float dx = p0[n] - m0, dy = p0[NPT + n] - m1, dz = p0[2 * NPT + n] - m2;
        mx = fmaxf(mx, dx * dx + dy * dy + dz * dz);
    }
    sm[tid] = mx; __syncthreads();
    for (int st = 128; st > 0; st >>= 1) {
        if (tid < st) sm[tid] = fmaxf(sm[tid], sm[tid + st]);
        __syncthreads();
    }
    if (tid == 0) part[96 + blockIdx.x] = sm[0];
}

// per-point normalized coords + voxel histogram; max-norm finalized inline from partials
__global__ void k_prep(const float* __restrict__ coords, const float* __restrict__ mean,
                       const float* __restrict__ part, float* __restrict__ cb3,
                       int* __restrict__ cursor) {
    int gid = blockIdx.x * 256 + threadIdx.x;
    int b = gid >> 16, n = gid & 65535;
    float mx = 0.f;
    #pragma unroll
    for (int c = 0; c < 8; c++) mx = fmaxf(mx, part[96 + b * 8 + c]);
    float inv = 0.5f / sqrtf(mx);
    float c0 = (coords[(size_t)(b * 3) * NPT + n]     - mean[b * 3])     * inv + 0.5f;
    float c1 = (coords[(size_t)(b * 3 + 1) * NPT + n] - mean[b * 3 + 1]) * inv + 0.5f;
    float c2 = (coords[(size_t)(b * 3 + 2) * NPT + n] - mean[b * 3 + 2]) * inv + 0.5f;
    c0 = fminf(fmaxf(c0 * 32.f, 0.f), 31.f);
    c1 = fminf(fmaxf(c1 * 32.f, 0.f), 31.f);
    c2 = fminf(fmaxf(c2 * 32.f, 0.f), 31.f);
    cb3[gid * 3]     = c0;
    cb3[gid * 3 + 1] = c1;
    cb3[gid * 3 + 2] = c2;
    int vx = b * R3 + ((int)rintf(c0) * 1024 + (int)rintf(c1) * 32 + (int)rintf(c2));
    atomicAdd(&cursor[vx], 1);
}

// scan stage 1: 256 blocks x 512 bins -> local exclusive scan + block totals
__global__ void k_scan1(int* __restrict__ cur, int* __restrict__ aux) {
    __shared__ int sm[256];
    int t = threadIdx.x;
    int base = blockIdx.x * 512 + t * 2;
    int c0 = cur[base], c1 = cur[base + 1];
    int s = c0 + c1;
    sm[t] = s; __syncthreads();
    for (int off = 1; off < 256; off <<= 1) {
        int v = (t >= off) ? sm[t - off] : 0;
        __syncthreads();
        sm[t] += v;
        __syncthreads();
    }
    int ex = sm[t] - s;
    cur[base] = ex;
    cur[base + 1] = ex + c0;
    if (t == 255) aux[blockIdx.x] = sm[t];
}

// scan stage 2+3 fused: each block reduces aux[0..blk) locally, adds offset
__global__ void k_scan3(int* __restrict__ cur, const int* __restrict__ aux) {
    __shared__ int sm[256];
    int t = threadIdx.x;
    sm[t] = (t < blockIdx.x) ? aux[t] : 0;
    __syncthreads();
    for (int off = 128; off > 0; off >>= 1) {
        if (t < off) sm[t] += sm[t + off];
        __syncthreads();
    }
    int add = sm[0];
    int base = blockIdx.x * 512 + t * 2;
    cur[base] += add;
    cur[base + 1] += add;
}

// features [B][64][N] fp32 -> FT [B][N][64] bf16 (LDS transpose)
__global__ __launch_bounds__(256) void k_trans(const float* __restrict__ feats,
                                               unsigned short* __restrict__ ft) {
    __shared__ float lds[64][65];
    int b = blockIdx.x >> 10;
    int n0 = (blockIdx.x & 1023) << 6;
    int tid = threadIdx.x;
    int nl = tid & 63;
    #pragma unroll
    for (int it = 0; it < 16; it++) {
        int ch = it * 4 + (tid >> 6);
        lds[nl][ch] = feats[((size_t)(b * 64 + ch) << 16) + n0 + nl];
    }
    __syncthreads();
    int nn = tid >> 2;
    int ch0 = (tid & 3) << 4;
    size_t obase = (((size_t)(b << 16) + n0 + nn) << 6) + ch0;
    short8 v0, v1;
    #pragma unroll
    for (int j = 0; j < 8; j++) v0[j] = (short)f2b(lds[nn][ch0 + j]);
    #pragma unroll
    for (int j = 0; j < 8; j++) v1[j] = (short)f2b(lds[nn][ch0 + 8 + j]);
    *(short8*)(ft + obase) = v0;
    *(short8*)(ft + obase + 8) = v1;
}

// place point ids into voxel-sorted order
__global__ void k_place(const float* __restrict__ cb3, int* __restrict__ cursor,
                        unsigned short* __restrict__ order) {
    int gid = blockIdx.x * 256 + threadIdx.x;
    int b = gid >> 16;
    float c0 = cb3[gid * 3], c1 = cb3[gid * 3 + 1], c2 = cb3[gid * 3 + 2];
    int vx = b * R3 + ((int)rintf(c0) * 1024 + (int)rintf(c1) * 32 + (int)rintf(c2));
    int slot = atomicAdd(&cursor[vx], 1);
    order[slot] = (unsigned short)(gid & 65535);
}

// one wave per voxel, point-parallel: lane = (point-slot p, ch-group g).
__global__ __launch_bounds__(256) void k_gather(const int* __restrict__ cursor,
        const unsigned short* __restrict__ order, const unsigned short* __restrict__ ft,
        unsigned short* __restrict__ g0) {
    int tid = threadIdx.x;
    int lane = tid & 63;
    int vx = blockIdx.x * 4 + (tid >> 6);
    int e = cursor[vx];
    int s = (vx == 0) ? 0 : cursor[vx - 1];
    int cnt = e - s;
    int p = lane >> 3;      // point slot 0..7
    int g = lane & 7;       // channel group 0..7 (8 channels each)
    int bb = vx >> 15;
    float acc[8] = {0.f, 0.f, 0.f, 0.f, 0.f, 0.f, 0.f, 0.f};
    for (int base = s; base < e; base += 8) {
        int idx = base + p;
        if (idx < e) {
            int n = order[idx];
            const unsigned short* fp = ft + (((size_t)(bb << 16) + n) << 6) + (g << 3);
            short8 v = *(const short8*)fp;
            #pragma unroll
            for (int j = 0; j < 8; j++) acc[j] += b2f((unsigned short)v[j]);
        }
    }
    #pragma unroll
    for (int j = 0; j < 8; j++) {
        acc[j] += __shfl_xor(acc[j], 8, 64);
        acc[j] += __shfl_xor(acc[j], 16, 64);
        acc[j] += __shfl_xor(acc[j], 32, 64);
    }
    if (p == 0) {
        float inv = 1.0f / (float)max(cnt, 1);
        int col = vx >> 5, z = vx & 31;
        short8 o8;
        #pragma unroll
        for (int j = 0; j < 8; j++) o8[j] = (short)f2b(acc[j] * inv);
        *(short8*)(g0 + (size_t)col * 2048 + (g << 8) + z * 8) = o8;
    }
}

// MFMA implicit-GEMM 3^3 conv, 4 columns/block, 512 threads / 8 waves.
// wave = (cp, nh, kh): column pair cp, out-ch half nh, K-half kh (ks in {2kh,2kh+1}).
// Tap loop FULLY UNROLLED: straight-line 108 MFMAs + 54 weight loads + 108 ds_reads
// per wave lets the compiler software-pipeline (front-load weight/LDS loads with
// counted vmcnt/lgkmcnt instead of paying full latency per tap).
// Split-K partials reduced via LDS (staging buffer reused); kh==0 waves finalize.
__global__ __launch_bounds__(512) void k_conv(const unsigned short* __restrict__ in,
        const unsigned short* __restrict__ w, const float* __restrict__ bias,
        const float* __restrict__ idF, float* __restrict__ outF,
        unsigned short* __restrict__ out, int zmaj) {
    __shared__ unsigned short sA[18 * 2048];    // 72 KB
    int tid = threadIdx.x;
    int lane = tid & 63;
    int wid = tid >> 6;        // 0..7
    int cp = wid & 1;          // column pair: y0+2cp, y0+2cp+1
    int nh = (wid >> 1) & 1;   // out-channel half
    int kh = wid >> 2;         // K-half
    int tile = blockIdx.x;     // 0..255
    int b = blockIdx.y;
    int x = tile >> 3;
    int y0 = (tile & 7) << 2;
    int t = tid & 255;
    int h = tid >> 8;          // half-block stages even/odd columns
    int sq = wid & 3;          // quarter-wave within the 256-group
    #pragma unroll 1
    for (int s2 = 0; s2 < 9; s2++) {
        int s = s2 * 2 + h;
        int gx = x + s / 6 - 1;
        int gy = y0 + s % 6 - 1;
        if ((unsigned)gx < 32u && (unsigned)gy < 32u) {
            const unsigned short* gsrc = in + (((size_t)b * 1024 + gx * 32 + gy) << 11)
                                            + ((size_t)t << 3);
            __builtin_amdgcn_global_load_lds(
                (const __attribute__((address_space(1))) unsigned int*)gsrc,
                (__attribute__((address_space(3))) unsigned int*)(sA + s * 2048 + (sq << 9)),
                16, 0, 0);
        } else {
            ((float4*)(sA + s * 2048))[t] = make_float4(0.f, 0.f, 0.f, 0.f);
        }
    }
    __syncthreads();
    f32x16 accA = {}, accB = {};
    const short8 zero8 = {0, 0, 0, 0, 0, 0, 0, 0};
    int half = lane >> 5;
    int z = lane & 31;
    #pragma unroll
    for (int c9 = 0; c9 < 9; c9++) {
        int dxi = c9 / 3, dyi = c9 % 3;
        int s0 = dxi * 6 + dyi + cp * 2;
        const unsigned short* acol0 = sA + s0 * 2048 + (half << 8) + kh * 1024;
        const unsigned short* wbase = w + (dxi * 9 + dyi * 3) * 4096 + nh * 512
                                        + kh * 2048 + lane * 8;
        #pragma unroll
        for (int dzi = 0; dzi < 3; dzi++) {
            int zz = z + dzi - 1;
            bool zv = (unsigned)zz < 32u;
            int zc = zv ? zz : 0;
            const unsigned short* ac0 = acol0 + zc * 8;
            const unsigned short* wp = wbase + dzi * 4096;
            #pragma unroll
            for (int ksi = 0; ksi < 2; ksi++) {
                short8 bf = *(const short8*)(wp + ksi * 1024);
                short8 a0 = *(const short8*)(ac0 + ksi * 512);
                short8 a1 = *(const short8*)(ac0 + 2048 + ksi * 512);
                if (!zv) { a0 = zero8; a1 = zero8; }
                accA = __builtin_amdgcn_mfma_f32_32x32x16_bf16(a0, bf, accA, 0, 0, 0);
                accB = __builtin_amdgcn_mfma_f32_32x32x16_bf16(a1, bf, accB, 0, 0, 0);
            }
        }
    }
    // split-K reduce across the kh wave pair, via LDS (reuse staging buffer)
    __syncthreads();
    float* RED = (float*)sA;
    if (kh == 1) {
        #pragma unroll
        for (int c = 0; c < 2; c++) {
            const f32x16& a = c ? accB : accA;
            #pragma unroll
            for (int rb = 0; rb < 4; rb++) {
                float4 v = make_float4(a[rb * 4], a[rb * 4 + 1], a[rb * 4 + 2], a[rb * 4 + 3]);
                ((float4*)(RED + ((((cp * 2 + nh) * 2 + c) * 4 + rb) << 8)))[lane] = v;
            }
        }
    }
    __syncthreads();
    if (kh == 0) {
        #pragma unroll
        for (int rb = 0; rb < 4; rb++) {
            float4 v0 = ((float4*)(RED + ((((cp * 2 + nh) * 2 + 0) * 4 + rb) << 8)))[lane];
            float4 v1 = ((float4*)(RED + ((((cp * 2 + nh) * 2 + 1) * 4 + rb) << 8)))[lane];
            accA[rb * 4]     += v0.x; accA[rb * 4 + 1] += v0.y;
            accA[rb * 4 + 2] += v0.z; accA[rb * 4 + 3] += v0.w;
            accB[rb * 4]     += v1.x; accB[rb * 4 + 1] += v1.y;
            accB[rb * 4 + 2] += v1.z; accB[rb * 4 + 3] += v1.w;
        }
        int o = nh * 32 + (lane & 31);
        float bb = bias[o];
        #pragma unroll
        for (int cc = 0; cc < 2; cc++) {
            int outcol = b * 1024 + x * 32 + (y0 + cp * 2 + cc);
            size_t cbase = (size_t)outcol << 11;
            size_t obase = cbase + (size_t)((o >> 3) << 8) + (o & 7);
            const f32x16& acc = cc ? accB : accA;
            #pragma unroll
            for (int r = 0; r < 16; r++) {
                int zr = (r & 3) + ((r >> 2) << 3) + ((lane >> 5) << 2);
                size_t oe = obase + (size_t)zr * 8;
                float v = acc[r] + bb;
                if (idF) v += idF[oe];
                v = fmaxf(v, 0.f);
                if (zmaj) out[cbase + (size_t)zr * 64 + o] = f2b(v);
                else out[oe] = f2b(v);
                if (outF) outF[oe] = v;
            }
        }
    }
}

// point-branch MLP via MFMA: pfeat[B][N][64] bf16 = relu(PW * feat + PB)
__global__ __launch_bounds__(256) void k_pfeat(const float* __restrict__ feats,
        const float* __restrict__ pb, const unsigned short* __restrict__ pwb,
        unsigned short* __restrict__ pf) {
    int tid = threadIdx.x;
    int lane = tid & 63;
    int wv = tid >> 6;
    int tile = blockIdx.x * 4 + wv;          // 0..8191
    int b = tile >> 11;
    int n0 = (tile & 2047) << 5;
    int m = lane & 31, kg = lane >> 5;
    const float* fb = feats + ((size_t)b << 22) + n0 + m;
    f32x16 acc0 = {}, acc1 = {};
    #pragma unroll
    for (int ks = 0; ks < 4; ks++) {
        short8 af;
        #pragma unroll
        for (int j = 0; j < 8; j++)
            af[j] = (short)f2b(fb[(size_t)(ks * 16 + kg * 8 + j) << 16]);
        short8 b0 = *(const short8*)(pwb + ((size_t)(ks * 64 + lane) << 3));
        short8 b1 = *(const short8*)(pwb + ((size_t)((4 + ks) * 64 + lane) << 3));
        acc0 = __builtin_amdgcn_mfma_f32_32x32x16_bf16(af, b0, acc0, 0, 0, 0);
        acc1 = __builtin_amdgcn_mfma_f32_32x32x16_bf16(af, b1, acc1, 0, 0, 0);
    }
    int och = lane & 31;
    float bias0 = pb[och], bias1 = pb[32 + och];
    #pragma unroll
    for (int r = 0; r < 16; r++) {
        int p = (r & 3) + ((r >> 2) << 3) + ((lane >> 5) << 2);
        size_t base = ((size_t)(b << 16) + n0 + p) << 6;
        pf[base + och]      = f2b(fmaxf(acc0[r] + bias0, 0.f));
        pf[base + 32 + och] = f2b(fmaxf(acc1[r] + bias1, 0.f));
    }
}

// devox gather (z-major grid) + pfeat load + collapsed attention + fuse.
// wave = 8 points x 8 channel-groups; per-corner loads coalesce to 8x128B segments.
__global__ __launch_bounds__(256) void k_final(const float* __restrict__ cb3,
        const unsigned short* __restrict__ gb, const unsigned short* __restrict__ pfeat,
        const float* __restrict__ ws, float* __restrict__ out) {
    int tid = threadIdx.x;
    int lane = tid & 63;
    int g = lane >> 3;      // channel group 0..7
    int p = lane & 7;       // point within wave
    int b = blockIdx.y;
    int n = (blockIdx.x << 5) + ((tid >> 6) << 3) + p;
    int gid = (b << 16) + n;
    float c0 = cb3[gid * 3], c1 = cb3[gid * 3 + 1], c2 = cb3[gid * 3 + 2];
    int lx = (int)floorf(c0), ly = (int)floorf(c1), lz = (int)floorf(c2);
    int hx = min(lx + 1, 31), hy = min(ly + 1, 31), hz = min(lz + 1, 31);
    float fx = c0 - (float)lx, fy = c1 - (float)ly, fz = c2 - (float)lz;
    int xs[2] = {lx, hx}; float wxx[2] = {1.f - fx, fx};
    int ys[2] = {ly, hy}; float wyy[2] = {1.f - fy, fy};
    int zs[2] = {lz, hz}; float wzz[2] = {1.f - fz, fz};
    float vf[8];
    #pragma unroll
    for (int j = 0; j < 8; j++) vf[j] = 0.f;
    #pragma unroll
    for (int ii = 0; ii < 2; ii++)
    #pragma unroll
    for (int jj = 0; jj < 2; jj++)
    #pragma unroll
    for (int kk = 0; kk < 2; kk++) {
        float wgt = wxx[ii] * wyy[jj] * wzz[kk];
        const unsigned short* gp = gb + (((size_t)b * 1024 + xs[ii] * 32 + ys[jj]) << 11)
                                      + zs[kk] * 64 + (g << 3);
        short8 v = *(const short8*)gp;
        #pragma unroll
        for (int j = 0; j < 8; j++) vf[j] += wgt * b2f((unsigned short)v[j]);
    }
    float pfv[8];
    const unsigned short* pp = pfeat + ((size_t)gid << 6) + (g << 3);
    short8 pv = *(const short8*)pp;
    #pragma unroll
    for (int j = 0; j < 8; j++) pfv[j] = b2f((unsigned short)pv[j]);
    const float* wae = ws + OFF_WAE + (g << 3);
    const float* wbe = ws + OFF_WBE + (g << 3);
    float part = 0.f;
    #pragma unroll
    for (int j = 0; j < 8; j++) part += wae[j] * vf[j] + wbe[j] * pfv[j];
    part += __shfl_xor(part, 8, 64);
    part += __shfl_xor(part, 16, 64);
    part += __shfl_xor(part, 32, 64);
    float q = part + ws[OFF_Q0];
    float attn = 1.0f + 1.0f / (1.0f + expf(-q));
    float* op = out + (((size_t)(b * 64 + (g << 3))) << 16) + n;
    #pragma unroll
    for (int j = 0; j < 8; j++) op[(size_t)j << 16] = vf[j] * attn + pfv[j];
}

extern "C" void kernel_launch(void* const* d_in, const int* in_sizes, int n_in,
                              void* d_out, int out_size, void* d_ws, size_t ws_size,
                              hipStream_t stream) {
    const float* features = (const float*)d_in[0];
    const float* coords   = (const float*)d_in[1];
    const float* vconv_w  = (const float*)d_in[2];
    const float* vconv_b  = (const float*)d_in[3];
    const float* vbn_g    = (const float*)d_in[4];
    const float* vbn_b    = (const float*)d_in[5];
    const float* res_w    = (const float*)d_in[6];
    const float* res_b    = (const float*)d_in[7];
    const float* res_bn_g = (const float*)d_in[8];
    const float* res_bn_b = (const float*)d_in[9];
    const float* pf_w     = (const float*)d_in[10];
    const float* pf_b     = (const float*)d_in[11];
    const float* pf_bn_g  = (const float*)d_in[12];
    const float* pf_bn_b  = (const float*)d_in[13];
    const float* attn_wa  = (const float*)d_in[14];
    const float* attn_ba  = (const float*)d_in[15];
    const float* attn_wb  = (const float*)d_in[16];
    const float* attn_bb  = (const float*)d_in[17];
    const float* attn_wc  = (const float*)d_in[18];
    const float* attn_bc  = (const float*)d_in[19];
    float* ws  = (float*)d_ws;
    float* out = (float*)d_out;

    unsigned short* WB  = (unsigned short*)(ws + OFF_WB16);
    unsigned short* PWB = (unsigned short*)(ws + OFF_PWB);
    int*            CUR = (int*)(ws + OFF_CUR);
    int*            AUX = (int*)(ws + OFF_AUX);
    unsigned short* ORD = (unsigned short*)(ws + OFF_ORD);
    unsigned short* FT  = (unsigned short*)(ws + OFF_GA);   // pre-conv overlay
    unsigned short* PF  = (unsigned short*)(ws + OFF_GA);   // post-conv overlay
    float* GA = ws + OFF_GA;
    unsigned short* G0 = (unsigned short*)(ws + OFF_G0);
    unsigned short* G1 = (unsigned short*)(ws + OFF_G1);
    const float* Bv = ws + OFF_BEFF;

    k_setup<<<2179, 256, 0, stream>>>(vconv_w, vconv_b, vbn_g, vbn_b, res_w, res_b,
                                      res_bn_g, res_bn_b, pf_w, pf_b, pf_bn_g, pf_bn_b,
                                      attn_wa, attn_ba, attn_wb, attn_bb, attn_wc, attn_bc, ws);
    k_mean1<<<96, 256, 0, stream>>>(coords, ws + OFF_PART, (float4*)CUR);
    k_maxn1<<<32, 256, 0, stream>>>(coords, ws + OFF_PART, ws + OFF_MEAN);
    k_prep<<<1024, 256, 0, stream>>>(coords, ws + OFF_MEAN, ws + OFF_PART,
                                     ws + OFF_CB3, CUR);
    k_scan1<<<256, 256, 0, stream>>>(CUR, AUX);
    k_scan3<<<256, 256, 0, stream>>>(CUR, AUX);
    k_trans<<<4096, 256, 0, stream>>>(features, FT);
    k_place<<<1024, 256, 0, stream>>>(ws + OFF_CB3, CUR, ORD);
    k_gather<<<32768, 256, 0, stream>>>(CUR, ORD, FT, G0);

    dim3 cg(256, 4);
    k_conv<<<cg, 512, 0, stream>>>(G0, WB + 0 * 110592, Bv + 0,   nullptr, GA,      G1, 0);
    k_conv<<<cg, 512, 0, stream>>>(G1, WB + 1 * 110592, Bv + 64,  nullptr, nullptr, G0, 0);
    k_conv<<<cg, 512, 0, stream>>>(G0, WB + 2 * 110592, Bv + 128, GA,      GA,      G1, 0);
    k_conv<<<cg, 512, 0, stream>>>(G1, WB + 3 * 110592, Bv + 192, nullptr, nullptr, G0, 0);
    k_conv<<<cg, 512, 0, stream>>>(G0, WB + 4 * 110592, Bv + 256, GA,      nullptr, G1, 1);

    k_pfeat<<<2048, 256, 0, stream>>>(features, ws + OFF_PB, PWB, PF);

    dim3 fg(2048, 4);
    k_final<<<fg, 256, 0, stream>>>(ws + OFF_CB3, G1, PF, ws, out);
}

// Round 4
// 526.092 us; speedup vs baseline: 1.0145x; 1.0145x over previous
//
#include <hip/hip_runtime.h>
#include <math.h>

#define NPT 65536
#define NB 4
#define R3 32768

typedef __attribute__((ext_vector_type(8))) short short8;
typedef __attribute__((ext_vector_type(16))) float f32x16;

// ws layout (float offsets)
#define OFF_WB16 0          // 276480 floats = 552960 bf16: 5 conv layers, B-frag order
#define OFF_BEFF 276480     // 5*64 conv biases (BN-folded)
#define OFF_PWB  276800     // 2048 floats = 4096 bf16: point-branch weights, B-frag order
#define OFF_PB   280896     // 64
#define OFF_WAE  280960     // 64
#define OFF_WBE  281024     // 64
#define OFF_Q0   281088     // 1 (+pad)
#define OFF_MEAN 281104     // 12
#define OFF_MAXN 281116     // 4
#define OFF_PART 281120     // 128 reduction partials (96 mean + 32 max)
#define OFF_AUX  281248     // 256 scan block sums (int)
#define OFF_CB3  281504     // 786432: 3 floats/point normalized coords
#define OFF_CUR  1067936    // 131072 int cursor
#define OFF_ORD  1199008    // 131072 floats = 262144 ushort sorted point ids
#define OFF_GA   1330080    // 8388608 fp32 residual; FT bf16 overlays pre-conv; PF bf16 overlays post-conv
#define OFF_G0   9718688    // 4194304 floats = 8388608 bf16 swizzled grid ping
#define OFF_G1   13912992   // 4194304 floats = 8388608 bf16 swizzled grid pong

__device__ __forceinline__ unsigned short f2b(float f) {
    union { float f; unsigned int u; } v; v.f = f;
    unsigned int r = v.u + 0x7fffu + ((v.u >> 16) & 1u);
    return (unsigned short)(r >> 16);
}
__device__ __forceinline__ float b2f(unsigned short u) {
    union { unsigned int u; float f; } v; v.u = ((unsigned int)u) << 16; return v.f;
}

// merged: conv-weight fold (idx < 552960) + misc param prep (idx >= 552960)
// conv weight layout (per layer, shorts): [tap 27][ks 4][nh 2][lane 64][j 8]
__global__ void k_setup(const float* __restrict__ vconv_w, const float* __restrict__ vconv_b,
                        const float* __restrict__ vbn_g, const float* __restrict__ vbn_b,
                        const float* __restrict__ res_w, const float* __restrict__ res_b,
                        const float* __restrict__ res_bn_g, const float* __restrict__ res_bn_b,
                        const float* __restrict__ pf_w, const float* __restrict__ pf_b,
                        const float* __restrict__ pf_bn_g, const float* __restrict__ pf_bn_b,
                        const float* __restrict__ wa, const float* __restrict__ ba,
                        const float* __restrict__ wb, const float* __restrict__ bb,
                        const float* __restrict__ wc, const float* __restrict__ bc,
                        float* __restrict__ ws) {
    int idx = blockIdx.x * 256 + threadIdx.x;
    const float invs = rsqrtf(1.00001f);
    if (idx < 552960) {
        unsigned short* wb16 = (unsigned short*)(ws + OFF_WB16);
        int j = idx & 7;
        int l = (idx >> 3) & 63;
        int nh = (idx >> 9) & 1;
        int ks = (idx >> 10) & 3;
        int rest = idx >> 12;          // layer*27 + t
        int t = rest % 27;
        int layer = rest / 27;
        int i = ks * 16 + ((l >> 5) << 3) + j;
        int o = nh * 32 + (l & 31);
        float scale, wsrc;
        if (layer == 0) {
            scale = vbn_g[o] * invs;
            wsrc = vconv_w[(o * 64 + i) * 27 + t];
        } else {
            scale = res_bn_g[(layer - 1) * 64 + o] * invs;
            wsrc = res_w[(size_t)(layer - 1) * 110592 + (o * 64 + i) * 27 + t];
        }
        wb16[idx] = f2b(wsrc * scale);
        return;
    }
    idx -= 552960;
    if (idx < 320) {
        int l = idx >> 6, o = idx & 63;
        float b_, g_, s_;
        if (l == 0) { b_ = vconv_b[o]; g_ = vbn_g[o]; s_ = vbn_b[o]; }
        else {
            b_ = res_b[(l - 1) * 64 + o];
            g_ = res_bn_g[(l - 1) * 64 + o];
            s_ = res_bn_b[(l - 1) * 64 + o];
        }
        ws[OFF_BEFF + idx] = b_ * g_ * invs + s_;
    } else if (idx < 4416) {
        int e = idx - 320;                 // 0..4095
        int j = e & 7;
        int lane = (e >> 3) & 63;
        int ks = (e >> 9) & 3;
        int half = e >> 11;
        int i = ks * 16 + ((lane >> 5) << 3) + j;
        int o = half * 32 + (lane & 31);
        ((unsigned short*)(ws + OFF_PWB))[e] = f2b(pf_w[o * 64 + i] * pf_bn_g[o] * invs);
    } else if (idx < 4480) {
        int o = idx - 4416;
        ws[OFF_PB + o] = pf_b[o] * pf_bn_g[o] * invs + pf_bn_b[o];
    } else if (idx < 4544) {
        int o = idx - 4480;
        float s = 0.f;
        for (int j = 0; j < 16; j++) s += wc[j] * wa[j * 64 + o];
        ws[OFF_WAE + o] = s;
    } else if (idx < 4608) {
        int o = idx - 4544;
        float s = 0.f;
        for (int j = 0; j < 16; j++) s += wc[16 + j] * wb[j * 64 + o];
        ws[OFF_WBE + o] = s;
    } else if (idx == 4608) {
        float s = bc[0];
        for (int j = 0; j < 16; j++) s += wc[j] * ba[j] + wc[16 + j] * bb[j];
        ws[OFF_Q0] = s;
    }
}

// stage-1 mean partials (96 blocks = 12 (b,d) x 8 chunks) + grid-stride zero of CUR
__global__ __launch_bounds__(256) void k_mean1(const float* __restrict__ coords,
                                               float* __restrict__ part,
                                               float4* __restrict__ curz) {
    for (int i = blockIdx.x * 256 + threadIdx.x; i < 32768; i += 96 * 256)
        curz[i] = make_float4(0.f, 0.f, 0.f, 0.f);
    __shared__ float sm[256];
    int bd = blockIdx.x >> 3, chunk = blockIdx.x & 7;
    int tid = threadIdx.x;
    const float* p = coords + (size_t)bd * NPT + chunk * 8192;
    float s = 0.f;
    for (int n = tid; n < 8192; n += 256) s += p[n];
    sm[tid] = s; __syncthreads();
    for (int st = 128; st > 0; st >>= 1) {
        if (tid < st) sm[tid] += sm[tid + st];
        __syncthreads();
    }
    if (tid == 0) part[blockIdx.x] = sm[0];
}

// stage-1 max-norm^2 partials (32 blocks = 4 b x 8 chunks); mean computed from partials inline.
// chunk-0 block stores mean for k_prep.
__global__ __launch_bounds__(256) void k_maxn1(const float* __restrict__ coords,
                                               float* __restrict__ part,
                                               float* __restrict__ mean) {
    __shared__ float sm[256];
    int b = blockIdx.x >> 3, chunk = blockIdx.x & 7;
    int tid = threadIdx.x;
    float m0 = 0.f, m1 = 0.f, m2 = 0.f;
    #pragma unroll
    for (int c = 0; c < 8; c++) {
        m0 += part[(b * 3 + 0) * 8 + c];
        m1 += part[(b * 3 + 1) * 8 + c];
        m2 += part[(b * 3 + 2) * 8 + c];
    }
    m0 *= (1.0f / NPT); m1 *= (1.0f / NPT); m2 *= (1.0f / NPT);
    if (chunk == 0 && tid == 0) {
        mean[b * 3] = m0; mean[b * 3 + 1] = m1; mean[b * 3 + 2] = m2;
    }
    const float* p0 = coords + (size_t)(b * 3) * NPT + chunk * 8192;
    float mx = 0.f;
    for (int n = tid; n < 8192; n += 256) {
        float dx = p0[n] - m0, dy = p0[NPT + n] - m1, dz = p0[2 * NPT + n] - m2;
        mx = fmaxf(mx, dx * dx + dy * dy + dz * dz);
    }
    sm[tid] = mx; __syncthreads();
    for (int st = 128; st > 0; st >>= 1) {
        if (tid < st) sm[tid] = fmaxf(sm[tid], sm[tid + st]);
        __syncthreads();
    }
    if (tid == 0) part[96 + blockIdx.x] = sm[0];
}

// per-point normalized coords + voxel histogram; max-norm finalized inline from partials
__global__ void k_prep(const float* __restrict__ coords, const float* __restrict__ mean,
                       const float* __restrict__ part, float* __restrict__ cb3,
                       int* __restrict__ cursor) {
    int gid = blockIdx.x * 256 + threadIdx.x;
    int b = gid >> 16, n = gid & 65535;
    float mx = 0.f;
    #pragma unroll
    for (int c = 0; c < 8; c++) mx = fmaxf(mx, part[96 + b * 8 + c]);
    float inv = 0.5f / sqrtf(mx);
    float c0 = (coords[(size_t)(b * 3) * NPT + n]     - mean[b * 3])     * inv + 0.5f;
    float c1 = (coords[(size_t)(b * 3 + 1) * NPT + n] - mean[b * 3 + 1]) * inv + 0.5f;
    float c2 = (coords[(size_t)(b * 3 + 2) * NPT + n] - mean[b * 3 + 2]) * inv + 0.5f;
    c0 = fminf(fmaxf(c0 * 32.f, 0.f), 31.f);
    c1 = fminf(fmaxf(c1 * 32.f, 0.f), 31.f);
    c2 = fminf(fmaxf(c2 * 32.f, 0.f), 31.f);
    cb3[gid * 3]     = c0;
    cb3[gid * 3 + 1] = c1;
    cb3[gid * 3 + 2] = c2;
    int vx = b * R3 + ((int)rintf(c0) * 1024 + (int)rintf(c1) * 32 + (int)rintf(c2));
    atomicAdd(&cursor[vx], 1);
}

// scan stage 1: 256 blocks x 512 bins -> local exclusive scan + block totals
__global__ void k_scan1(int* __restrict__ cur, int* __restrict__ aux) {
    __shared__ int sm[256];
    int t = threadIdx.x;
    int base = blockIdx.x * 512 + t * 2;
    int c0 = cur[base], c1 = cur[base + 1];
    int s = c0 + c1;
    sm[t] = s; __syncthreads();
    for (int off = 1; off < 256; off <<= 1) {
        int v = (t >= off) ? sm[t - off] : 0;
        __syncthreads();
        sm[t] += v;
        __syncthreads();
    }
    int ex = sm[t] - s;
    cur[base] = ex;
    cur[base + 1] = ex + c0;
    if (t == 255) aux[blockIdx.x] = sm[t];
}

// scan stage 2+3 fused: each block reduces aux[0..blk) locally, adds offset
__global__ void k_scan3(int* __restrict__ cur, const int* __restrict__ aux) {
    __shared__ int sm[256];
    int t = threadIdx.x;
    sm[t] = (t < blockIdx.x) ? aux[t] : 0;
    __syncthreads();
    for (int off = 128; off > 0; off >>= 1) {
        if (t < off) sm[t] += sm[t + off];
        __syncthreads();
    }
    int add = sm[0];
    int base = blockIdx.x * 512 + t * 2;
    cur[base] += add;
    cur[base + 1] += add;
}

// features [B][64][N] fp32 -> FT [B][N][64] bf16 (LDS transpose)
__global__ __launch_bounds__(256) void k_trans(const float* __restrict__ feats,
                                               unsigned short* __restrict__ ft) {
    __shared__ float lds[64][65];
    int b = blockIdx.x >> 10;
    int n0 = (blockIdx.x & 1023) << 6;
    int tid = threadIdx.x;
    int nl = tid & 63;
    #pragma unroll
    for (int it = 0; it < 16; it++) {
        int ch = it * 4 + (tid >> 6);
        lds[nl][ch] = feats[((size_t)(b * 64 + ch) << 16) + n0 + nl];
    }
    __syncthreads();
    int nn = tid >> 2;
    int ch0 = (tid & 3) << 4;
    size_t obase = (((size_t)(b << 16) + n0 + nn) << 6) + ch0;
    short8 v0, v1;
    #pragma unroll
    for (int j = 0; j < 8; j++) v0[j] = (short)f2b(lds[nn][ch0 + j]);
    #pragma unroll
    for (int j = 0; j < 8; j++) v1[j] = (short)f2b(lds[nn][ch0 + 8 + j]);
    *(short8*)(ft + obase) = v0;
    *(short8*)(ft + obase + 8) = v1;
}

// place point ids into voxel-sorted order
__global__ void k_place(const float* __restrict__ cb3, int* __restrict__ cursor,
                        unsigned short* __restrict__ order) {
    int gid = blockIdx.x * 256 + threadIdx.x;
    int b = gid >> 16;
    float c0 = cb3[gid * 3], c1 = cb3[gid * 3 + 1], c2 = cb3[gid * 3 + 2];
    int vx = b * R3 + ((int)rintf(c0) * 1024 + (int)rintf(c1) * 32 + (int)rintf(c2));
    int slot = atomicAdd(&cursor[vx], 1);
    order[slot] = (unsigned short)(gid & 65535);
}

// one wave per voxel, point-parallel: lane = (point-slot p, ch-group g).
__global__ __launch_bounds__(256) void k_gather(const int* __restrict__ cursor,
        const unsigned short* __restrict__ order, const unsigned short* __restrict__ ft,
        unsigned short* __restrict__ g0) {
    int tid = threadIdx.x;
    int lane = tid & 63;
    int vx = blockIdx.x * 4 + (tid >> 6);
    int e = cursor[vx];
    int s = (vx == 0) ? 0 : cursor[vx - 1];
    int cnt = e - s;
    int p = lane >> 3;      // point slot 0..7
    int g = lane & 7;       // channel group 0..7 (8 channels each)
    int bb = vx >> 15;
    float acc[8] = {0.f, 0.f, 0.f, 0.f, 0.f, 0.f, 0.f, 0.f};
    for (int base = s; base < e; base += 8) {
        int idx = base + p;
        if (idx < e) {
            int n = order[idx];
            const unsigned short* fp = ft + (((size_t)(bb << 16) + n) << 6) + (g << 3);
            short8 v = *(const short8*)fp;
            #pragma unroll
            for (int j = 0; j < 8; j++) acc[j] += b2f((unsigned short)v[j]);
        }
    }
    #pragma unroll
    for (int j = 0; j < 8; j++) {
        acc[j] += __shfl_xor(acc[j], 8, 64);
        acc[j] += __shfl_xor(acc[j], 16, 64);
        acc[j] += __shfl_xor(acc[j], 32, 64);
    }
    if (p == 0) {
        float inv = 1.0f / (float)max(cnt, 1);
        int col = vx >> 5, z = vx & 31;
        short8 o8;
        #pragma unroll
        for (int j = 0; j < 8; j++) o8[j] = (short)f2b(acc[j] * inv);
        *(short8*)(g0 + (size_t)col * 2048 + (g << 8) + z * 8) = o8;
    }
}

// MFMA implicit-GEMM 3^3 conv, 4 columns/block, 512 threads / 8 waves.
// wave = (cp, nh, kh): column pair cp, out-ch half nh, K-half kh (ks in {2kh,2kh+1}).
// Fully-unrolled tap loop + EXPLICIT double-buffered weight prefetch in registers:
// tap 0's 6 weight loads issue before the staging barrier (overlap with
// global_load_lds wait); tap t+1's loads issue before tap t's 12 MFMAs, so the
// ~300cyc L2 latency is covered by real work instead of a just-in-time stall
// (R3 showed the compiler won't do this on its own: VGPR stayed 52).
// Split-K partials reduced via LDS (staging buffer reused); kh==0 waves finalize.
__global__ __launch_bounds__(512) void k_conv(const unsigned short* __restrict__ in,
        const unsigned short* __restrict__ w, const float* __restrict__ bias,
        const float* __restrict__ idF, float* __restrict__ outF,
        unsigned short* __restrict__ out, int zmaj) {
    __shared__ unsigned short sA[18 * 2048];    // 72 KB
    int tid = threadIdx.x;
    int lane = tid & 63;
    int wid = tid >> 6;        // 0..7
    int cp = wid & 1;          // column pair: y0+2cp, y0+2cp+1
    int nh = (wid >> 1) & 1;   // out-channel half
    int kh = wid >> 2;         // K-half
    int tile = blockIdx.x;     // 0..255
    int b = blockIdx.y;
    int x = tile >> 3;
    int y0 = (tile & 7) << 2;
    int t = tid & 255;
    int h = tid >> 8;          // half-block stages even/odd columns
    int sq = wid & 3;          // quarter-wave within the 256-group

    // per-wave weight base: layout [tap 27][ks 4][nh 2][lane 64][j 8]
    const unsigned short* wl = w + nh * 512 + kh * 2048 + lane * 8;
    short8 wreg[2][6];         // [buf][dzi*2+ksi]; indices constant after unroll
    #pragma unroll
    for (int e = 0; e < 6; e++)
        wreg[0][e] = *(const short8*)(wl + (e >> 1) * 4096 + (e & 1) * 1024);

    #pragma unroll 1
    for (int s2 = 0; s2 < 9; s2++) {
        int s = s2 * 2 + h;
        int gx = x + s / 6 - 1;
        int gy = y0 + s % 6 - 1;
        if ((unsigned)gx < 32u && (unsigned)gy < 32u) {
            const unsigned short* gsrc = in + (((size_t)b * 1024 + gx * 32 + gy) << 11)
                                            + ((size_t)t << 3);
            __builtin_amdgcn_global_load_lds(
                (const __attribute__((address_space(1))) unsigned int*)gsrc,
                (__attribute__((address_space(3))) unsigned int*)(sA + s * 2048 + (sq << 9)),
                16, 0, 0);
        } else {
            ((float4*)(sA + s * 2048))[t] = make_float4(0.f, 0.f, 0.f, 0.f);
        }
    }
    __syncthreads();
    f32x16 accA = {}, accB = {};
    const short8 zero8 = {0, 0, 0, 0, 0, 0, 0, 0};
    int half = lane >> 5;
    int z = lane & 31;
    #pragma unroll
    for (int c9 = 0; c9 < 9; c9++) {
        // prefetch next tap-group's weights one group ahead
        if (c9 < 8) {
            const unsigned short* wpt = wl + (c9 + 1) * 12288;
            #pragma unroll
            for (int e = 0; e < 6; e++)
                wreg[(c9 + 1) & 1][e] = *(const short8*)(wpt + (e >> 1) * 4096 + (e & 1) * 1024);
        }
        int dxi = c9 / 3, dyi = c9 % 3;
        int s0 = dxi * 6 + dyi + cp * 2;
        const unsigned short* acol0 = sA + s0 * 2048 + (half << 8) + kh * 1024;
        #pragma unroll
        for (int dzi = 0; dzi < 3; dzi++) {
            int zz = z + dzi - 1;
            bool zv = (unsigned)zz < 32u;
            int zc = zv ? zz : 0;
            const unsigned short* ac0 = acol0 + zc * 8;
            #pragma unroll
            for (int ksi = 0; ksi < 2; ksi++) {
                short8 bf = wreg[c9 & 1][dzi * 2 + ksi];
                short8 a0 = *(const short8*)(ac0 + ksi * 512);
                short8 a1 = *(const short8*)(ac0 + 2048 + ksi * 512);
                if (!zv) { a0 = zero8; a1 = zero8; }
                accA = __builtin_amdgcn_mfma_f32_32x32x16_bf16(a0, bf, accA, 0, 0, 0);
                accB = __builtin_amdgcn_mfma_f32_32x32x16_bf16(a1, bf, accB, 0, 0, 0);
            }
        }
    }
    // split-K reduce across the kh wave pair, via LDS (reuse staging buffer)
    __syncthreads();
    float* RED = (float*)sA;
    if (kh == 1) {
        #pragma unroll
        for (int c = 0; c < 2; c++) {
            const f32x16& a = c ? accB : accA;
            #pragma unroll
            for (int rb = 0; rb < 4; rb++) {
                float4 v = make_float4(a[rb * 4], a[rb * 4 + 1], a[rb * 4 + 2], a[rb * 4 + 3]);
                ((float4*)(RED + ((((cp * 2 + nh) * 2 + c) * 4 + rb) << 8)))[lane] = v;
            }
        }
    }
    __syncthreads();
    if (kh == 0) {
        #pragma unroll
        for (int rb = 0; rb < 4; rb++) {
            float4 v0 = ((float4*)(RED + ((((cp * 2 + nh) * 2 + 0) * 4 + rb) << 8)))[lane];
            float4 v1 = ((float4*)(RED + ((((cp * 2 + nh) * 2 + 1) * 4 + rb) << 8)))[lane];
            accA[rb * 4]     += v0.x; accA[rb * 4 + 1] += v0.y;
            accA[rb * 4 + 2] += v0.z; accA[rb * 4 + 3] += v0.w;
            accB[rb * 4]     += v1.x; accB[rb * 4 + 1] += v1.y;
            accB[rb * 4 + 2] += v1.z; accB[rb * 4 + 3] += v1.w;
        }
        int o = nh * 32 + (lane & 31);
        float bb = bias[o];
        #pragma unroll
        for (int cc = 0; cc < 2; cc++) {
            int outcol = b * 1024 + x * 32 + (y0 + cp * 2 + cc);
            size_t cbase = (size_t)outcol << 11;
            size_t obase = cbase + (size_t)((o >> 3) << 8) + (o & 7);
            const f32x16& acc = cc ? accB : accA;
            #pragma unroll
            for (int r = 0; r < 16; r++) {
                int zr = (r & 3) + ((r >> 2) << 3) + ((lane >> 5) << 2);
                size_t oe = obase + (size_t)zr * 8;
                float v = acc[r] + bb;
                if (idF) v += idF[oe];
                v = fmaxf(v, 0.f);
                if (zmaj) out[cbase + (size_t)zr * 64 + o] = f2b(v);
                else out[oe] = f2b(v);
                if (outF) outF[oe] = v;
            }
        }
    }
}

// point-branch MLP via MFMA: pfeat[B][N][64] bf16 = relu(PW * feat + PB)
__global__ __launch_bounds__(256) void k_pfeat(const float* __restrict__ feats,
        const float* __restrict__ pb, const unsigned short* __restrict__ pwb,
        unsigned short* __restrict__ pf) {
    int tid = threadIdx.x;
    int lane = tid & 63;
    int wv = tid >> 6;
    int tile = blockIdx.x * 4 + wv;          // 0..8191
    int b = tile >> 11;
    int n0 = (tile & 2047) << 5;
    int m = lane & 31, kg = lane >> 5;
    const float* fb = feats + ((size_t)b << 22) + n0 + m;
    f32x16 acc0 = {}, acc1 = {};
    #pragma unroll
    for (int ks = 0; ks < 4; ks++) {
        short8 af;
        #pragma unroll
        for (int j = 0; j < 8; j++)
            af[j] = (short)f2b(fb[(size_t)(ks * 16 + kg * 8 + j) << 16]);
        short8 b0 = *(const short8*)(pwb + ((size_t)(ks * 64 + lane) << 3));
        short8 b1 = *(const short8*)(pwb + ((size_t)((4 + ks) * 64 + lane) << 3));
        acc0 = __builtin_amdgcn_mfma_f32_32x32x16_bf16(af, b0, acc0, 0, 0, 0);
        acc1 = __builtin_amdgcn_mfma_f32_32x32x16_bf16(af, b1, acc1, 0, 0, 0);
    }
    int och = lane & 31;
    float bias0 = pb[och], bias1 = pb[32 + och];
    #pragma unroll
    for (int r = 0; r < 16; r++) {
        int p = (r & 3) + ((r >> 2) << 3) + ((lane >> 5) << 2);
        size_t base = ((size_t)(b << 16) + n0 + p) << 6;
        pf[base + och]      = f2b(fmaxf(acc0[r] + bias0, 0.f));
        pf[base + 32 + och] = f2b(fmaxf(acc1[r] + bias1, 0.f));
    }
}

// devox gather (z-major grid) + pfeat load + collapsed attention + fuse.
// wave = 8 points x 8 channel-groups; per-corner loads coalesce to 8x128B segments.
__global__ __launch_bounds__(256) void k_final(const float* __restrict__ cb3,
        const unsigned short* __restrict__ gb, const unsigned short* __restrict__ pfeat,
        const float* __restrict__ ws, float* __restrict__ out) {
    int tid = threadIdx.x;
    int lane = tid & 63;
    int g = lane >> 3;      // channel group 0..7
    int p = lane & 7;       // point within wave
    int b = blockIdx.y;
    int n = (blockIdx.x << 5) + ((tid >> 6) << 3) + p;
    int gid = (b << 16) + n;
    float c0 = cb3[gid * 3], c1 = cb3[gid * 3 + 1], c2 = cb3[gid * 3 + 2];
    int lx = (int)floorf(c0), ly = (int)floorf(c1), lz = (int)floorf(c2);
    int hx = min(lx + 1, 31), hy = min(ly + 1, 31), hz = min(lz + 1, 31);
    float fx = c0 - (float)lx, fy = c1 - (float)ly, fz = c2 - (float)lz;
    int xs[2] = {lx, hx}; float wxx[2] = {1.f - fx, fx};
    int ys[2] = {ly, hy}; float wyy[2] = {1.f - fy, fy};
    int zs[2] = {lz, hz}; float wzz[2] = {1.f - fz, fz};
    float vf[8];
    #pragma unroll
    for (int j = 0; j < 8; j++) vf[j] = 0.f;
    #pragma unroll
    for (int ii = 0; ii < 2; ii++)
    #pragma unroll
    for (int jj = 0; jj < 2; jj++)
    #pragma unroll
    for (int kk = 0; kk < 2; kk++) {
        float wgt = wxx[ii] * wyy[jj] * wzz[kk];
        const unsigned short* gp = gb + (((size_t)b * 1024 + xs[ii] * 32 + ys[jj]) << 11)
                                      + zs[kk] * 64 + (g << 3);
        short8 v = *(const short8*)gp;
        #pragma unroll
        for (int j = 0; j < 8; j++) vf[j] += wgt * b2f((unsigned short)v[j]);
    }
    float pfv[8];
    const unsigned short* pp = pfeat + ((size_t)gid << 6) + (g << 3);
    short8 pv = *(const short8*)pp;
    #pragma unroll
    for (int j = 0; j < 8; j++) pfv[j] = b2f((unsigned short)pv[j]);
    const float* wae = ws + OFF_WAE + (g << 3);
    const float* wbe = ws + OFF_WBE + (g << 3);
    float part = 0.f;
    #pragma unroll
    for (int j = 0; j < 8; j++) part += wae[j] * vf[j] + wbe[j] * pfv[j];
    part += __shfl_xor(part, 8, 64);
    part += __shfl_xor(part, 16, 64);
    part += __shfl_xor(part, 32, 64);
    float q = part + ws[OFF_Q0];
    float attn = 1.0f + 1.0f / (1.0f + expf(-q));
    float* op = out + (((size_t)(b * 64 + (g << 3))) << 16) + n;
    #pragma unroll
    for (int j = 0; j < 8; j++) op[(size_t)j << 16] = vf[j] * attn + pfv[j];
}

extern "C" void kernel_launch(void* const* d_in, const int* in_sizes, int n_in,
                              void* d_out, int out_size, void* d_ws, size_t ws_size,
                              hipStream_t stream) {
    const float* features = (const float*)d_in[0];
    const float* coords   = (const float*)d_in[1];
    const float* vconv_w  = (const float*)d_in[2];
    const float* vconv_b  = (const float*)d_in[3];
    const float* vbn_g    = (const float*)d_in[4];
    const float* vbn_b    = (const float*)d_in[5];
    const float* res_w    = (const float*)d_in[6];
    const float* res_b    = (const float*)d_in[7];
    const float* res_bn_g = (const float*)d_in[8];
    const float* res_bn_b = (const float*)d_in[9];
    const float* pf_w     = (const float*)d_in[10];
    const float* pf_b     = (const float*)d_in[11];
    const float* pf_bn_g  = (const float*)d_in[12];
    const float* pf_bn_b  = (const float*)d_in[13];
    const float* attn_wa  = (const float*)d_in[14];
    const float* attn_ba  = (const float*)d_in[15];
    const float* attn_wb  = (const float*)d_in[16];
    const float* attn_bb  = (const float*)d_in[17];
    const float* attn_wc  = (const float*)d_in[18];
    const float* attn_bc  = (const float*)d_in[19];
    float* ws  = (float*)d_ws;
    float* out = (float*)d_out;

    unsigned short* WB  = (unsigned short*)(ws + OFF_WB16);
    unsigned short* PWB = (unsigned short*)(ws + OFF_PWB);
    int*            CUR = (int*)(ws + OFF_CUR);
    int*            AUX = (int*)(ws + OFF_AUX);
    unsigned short* ORD = (unsigned short*)(ws + OFF_ORD);
    unsigned short* FT  = (unsigned short*)(ws + OFF_GA);   // pre-conv overlay
    unsigned short* PF  = (unsigned short*)(ws + OFF_GA);   // post-conv overlay
    float* GA = ws + OFF_GA;
    unsigned short* G0 = (unsigned short*)(ws + OFF_G0);
    unsigned short* G1 = (unsigned short*)(ws + OFF_G1);
    const float* Bv = ws + OFF_BEFF;

    k_setup<<<2179, 256, 0, stream>>>(vconv_w, vconv_b, vbn_g, vbn_b, res_w, res_b,
                                      res_bn_g, res_bn_b, pf_w, pf_b, pf_bn_g, pf_bn_b,
                                      attn_wa, attn_ba, attn_wb, attn_bb, attn_wc, attn_bc, ws);
    k_mean1<<<96, 256, 0, stream>>>(coords, ws + OFF_PART, (float4*)CUR);
    k_maxn1<<<32, 256, 0, stream>>>(coords, ws + OFF_PART, ws + OFF_MEAN);
    k_prep<<<1024, 256, 0, stream>>>(coords, ws + OFF_MEAN, ws + OFF_PART,
                                     ws + OFF_CB3, CUR);
    k_scan1<<<256, 256, 0, stream>>>(CUR, AUX);
    k_scan3<<<256, 256, 0, stream>>>(CUR, AUX);
    k_trans<<<4096, 256, 0, stream>>>(features, FT);
    k_place<<<1024, 256, 0, stream>>>(ws + OFF_CB3, CUR, ORD);
    k_gather<<<32768, 256, 0, stream>>>(CUR, ORD, FT, G0);

    dim3 cg(256, 4);
    k_conv<<<cg, 512, 0, stream>>>(G0, WB + 0 * 110592, Bv + 0,   nullptr, GA,      G1, 0);
    k_conv<<<cg, 512, 0, stream>>>(G1, WB + 1 * 110592, Bv + 64,  nullptr, nullptr, G0, 0);
    k_conv<<<cg, 512, 0, stream>>>(G0, WB + 2 * 110592, Bv + 128, GA,      GA,      G1, 0);
    k_conv<<<cg, 512, 0, stream>>>(G1, WB + 3 * 110592, Bv + 192, nullptr, nullptr, G0, 0);
    k_conv<<<cg, 512, 0, stream>>>(G0, WB + 4 * 110592, Bv + 256, GA,      nullptr, G1, 1);

    k_pfeat<<<2048, 256, 0, stream>>>(features, ws + OFF_PB, PWB, PF);

    dim3 fg(2048, 4);
    k_final<<<fg, 256, 0, stream>>>(ws + OFF_CB3, G1, PF, ws, out);
}

// Round 5
// 514.601 us; speedup vs baseline: 1.0372x; 1.0223x over previous
//
#include <hip/hip_runtime.h>
#include <math.h>

#define NPT 65536
#define NB 4
#define R3 32768

typedef __attribute__((ext_vector_type(8))) short short8;
typedef __attribute__((ext_vector_type(16))) float f32x16;

// ws layout (float offsets)
#define OFF_WB16 0          // 276480 floats = 552960 bf16: 5 conv layers, B-frag order
#define OFF_BEFF 276480     // 5*64 conv biases (BN-folded)
#define OFF_PWB  276800     // 2048 floats = 4096 bf16: point-branch weights, B-frag order
#define OFF_PB   280896     // 64
#define OFF_WAE  280960     // 64
#define OFF_WBE  281024     // 64
#define OFF_Q0   281088     // 1 (+pad)
#define OFF_MEAN 281104     // 12
#define OFF_MAXN 281116     // 4
#define OFF_PART 281120     // 128 reduction partials (96 mean + 32 max)
#define OFF_AUX  281248     // 256 scan block sums (int)
#define OFF_CB3  281504     // 786432: 3 floats/point normalized coords
#define OFF_CUR  1067936    // 131072 int cursor
#define OFF_ORD  1199008    // 131072 floats = 262144 ushort sorted point ids
#define OFF_GA   1330080    // 8388608 fp32 residual; FT bf16 overlays pre-conv; PF bf16 overlays post-conv
#define OFF_G0   9718688    // 4194304 floats = 8388608 bf16 swizzled grid ping
#define OFF_G1   13912992   // 4194304 floats = 8388608 bf16 swizzled grid pong

__device__ __forceinline__ unsigned short f2b(float f) {
    union { float f; unsigned int u; } v; v.f = f;
    unsigned int r = v.u + 0x7fffu + ((v.u >> 16) & 1u);
    return (unsigned short)(r >> 16);
}
__device__ __forceinline__ float b2f(unsigned short u) {
    union { unsigned int u; float f; } v; v.u = ((unsigned int)u) << 16; return v.f;
}

// merged: conv-weight fold (idx < 552960) + misc param prep (idx >= 552960)
// conv weight layout (per layer, shorts): [tap 27][ks 4][nh 2][lane 64][j 8]
__global__ void k_setup(const float* __restrict__ vconv_w, const float* __restrict__ vconv_b,
                        const float* __restrict__ vbn_g, const float* __restrict__ vbn_b,
                        const float* __restrict__ res_w, const float* __restrict__ res_b,
                        const float* __restrict__ res_bn_g, const float* __restrict__ res_bn_b,
                        const float* __restrict__ pf_w, const float* __restrict__ pf_b,
                        const float* __restrict__ pf_bn_g, const float* __restrict__ pf_bn_b,
                        const float* __restrict__ wa, const float* __restrict__ ba,
                        const float* __restrict__ wb, const float* __restrict__ bb,
                        const float* __restrict__ wc, const float* __restrict__ bc,
                        float* __restrict__ ws) {
    int idx = blockIdx.x * 256 + threadIdx.x;
    const float invs = rsqrtf(1.00001f);
    if (idx < 552960) {
        unsigned short* wb16 = (unsigned short*)(ws + OFF_WB16);
        int j = idx & 7;
        int l = (idx >> 3) & 63;
        int nh = (idx >> 9) & 1;
        int ks = (idx >> 10) & 3;
        int rest = idx >> 12;          // layer*27 + t
        int t = rest % 27;
        int layer = rest / 27;
        int i = ks * 16 + ((l >> 5) << 3) + j;
        int o = nh * 32 + (l & 31);
        float scale, wsrc;
        if (layer == 0) {
            scale = vbn_g[o] * invs;
            wsrc = vconv_w[(o * 64 + i) * 27 + t];
        } else {
            scale = res_bn_g[(layer - 1) * 64 + o] * invs;
            wsrc = res_w[(size_t)(layer - 1) * 110592 + (o * 64 + i) * 27 + t];
        }
        wb16[idx] = f2b(wsrc * scale);
        return;
    }
    idx -= 552960;
    if (idx < 320) {
        int l = idx >> 6, o = idx & 63;
        float b_, g_, s_;
        if (l == 0) { b_ = vconv_b[o]; g_ = vbn_g[o]; s_ = vbn_b[o]; }
        else {
            b_ = res_b[(l - 1) * 64 + o];
            g_ = res_bn_g[(l - 1) * 64 + o];
            s_ = res_bn_b[(l - 1) * 64 + o];
        }
        ws[OFF_BEFF + idx] = b_ * g_ * invs + s_;
    } else if (idx < 4416) {
        int e = idx - 320;                 // 0..4095
        int j = e & 7;
        int lane = (e >> 3) & 63;
        int ks = (e >> 9) & 3;
        int half = e >> 11;
        int i = ks * 16 + ((lane >> 5) << 3) + j;
        int o = half * 32 + (lane & 31);
        ((unsigned short*)(ws + OFF_PWB))[e] = f2b(pf_w[o * 64 + i] * pf_bn_g[o] * invs);
    } else if (idx < 4480) {
        int o = idx - 4416;
        ws[OFF_PB + o] = pf_b[o] * pf_bn_g[o] * invs + pf_bn_b[o];
    } else if (idx < 4544) {
        int o = idx - 4480;
        float s = 0.f;
        for (int j = 0; j < 16; j++) s += wc[j] * wa[j * 64 + o];
        ws[OFF_WAE + o] = s;
    } else if (idx < 4608) {
        int o = idx - 4544;
        float s = 0.f;
        for (int j = 0; j < 16; j++) s += wc[16 + j] * wb[j * 64 + o];
        ws[OFF_WBE + o] = s;
    } else if (idx == 4608) {
        float s = bc[0];
        for (int j = 0; j < 16; j++) s += wc[j] * ba[j] + wc[16 + j] * bb[j];
        ws[OFF_Q0] = s;
    }
}

// stage-1 mean partials (96 blocks = 12 (b,d) x 8 chunks) + grid-stride zero of CUR
__global__ __launch_bounds__(256) void k_mean1(const float* __restrict__ coords,
                                               float* __restrict__ part,
                                               float4* __restrict__ curz) {
    for (int i = blockIdx.x * 256 + threadIdx.x; i < 32768; i += 96 * 256)
        curz[i] = make_float4(0.f, 0.f, 0.f, 0.f);
    __shared__ float sm[256];
    int bd = blockIdx.x >> 3, chunk = blockIdx.x & 7;
    int tid = threadIdx.x;
    const float* p = coords + (size_t)bd * NPT + chunk * 8192;
    float s = 0.f;
    for (int n = tid; n < 8192; n += 256) s += p[n];
    sm[tid] = s; __syncthreads();
    for (int st = 128; st > 0; st >>= 1) {
        if (tid < st) sm[tid] += sm[tid + st];
        __syncthreads();
    }
    if (tid == 0) part[blockIdx.x] = sm[0];
}

// stage-1 max-norm^2 partials (32 blocks = 4 b x 8 chunks); mean computed from partials inline.
// chunk-0 block stores mean for k_prep.
__global__ __launch_bounds__(256) void k_maxn1(const float* __restrict__ coords,
                                               float* __restrict__ part,
                                               float* __restrict__ mean) {
    __shared__ float sm[256];
    int b = blockIdx.x >> 3, chunk = blockIdx.x & 7;
    int tid = threadIdx.x;
    float m0 = 0.f, m1 = 0.f, m2 = 0.f;
    #pragma unroll
    for (int c = 0; c < 8; c++) {
        m0 += part[(b * 3 + 0) * 8 + c];
        m1 += part[(b * 3 + 1) * 8 + c];
        m2 += part[(b * 3 + 2) * 8 + c];
    }
    m0 *= (1.0f / NPT); m1 *= (1.0f / NPT); m2 *= (1.0f / NPT);
    if (chunk == 0 && tid == 0) {
        mean[b * 3] = m0; mean[b * 3 + 1] = m1; mean[b * 3 + 2] = m2;
    }
    const float* p0 = coords + (size_t)(b * 3) * NPT + chunk * 8192;
    float mx = 0.f;
    for (int n = tid; n < 8192; n += 256) {
        float dx = p0[n] - m0, dy = p0[NPT + n] - m1, dz = p0[2 * NPT + n] - m2;
        mx = fmaxf(mx, dx * dx + dy * dy + dz * dz);
    }
    sm[tid] = mx; __syncthreads();
    for (int st = 128; st > 0; st >>= 1) {
        if (tid < st) sm[tid] = fmaxf(sm[tid], sm[tid + st]);
        __syncthreads();
    }
    if (tid == 0) part[96 + blockIdx.x] = sm[0];
}

// per-point normalized coords + voxel histogram; max-norm finalized inline from partials
__global__ void k_prep(const float* __restrict__ coords, const float* __restrict__ mean,
                       const float* __restrict__ part, float* __restrict__ cb3,
                       int* __restrict__ cursor) {
    int gid = blockIdx.x * 256 + threadIdx.x;
    int b = gid >> 16, n = gid & 65535;
    float mx = 0.f;
    #pragma unroll
    for (int c = 0; c < 8; c++) mx = fmaxf(mx, part[96 + b * 8 + c]);
    float inv = 0.5f / sqrtf(mx);
    float c0 = (coords[(size_t)(b * 3) * NPT + n]     - mean[b * 3])     * inv + 0.5f;
    float c1 = (coords[(size_t)(b * 3 + 1) * NPT + n] - mean[b * 3 + 1]) * inv + 0.5f;
    float c2 = (coords[(size_t)(b * 3 + 2) * NPT + n] - mean[b * 3 + 2]) * inv + 0.5f;
    c0 = fminf(fmaxf(c0 * 32.f, 0.f), 31.f);
    c1 = fminf(fmaxf(c1 * 32.f, 0.f), 31.f);
    c2 = fminf(fmaxf(c2 * 32.f, 0.f), 31.f);
    cb3[gid * 3]     = c0;
    cb3[gid * 3 + 1] = c1;
    cb3[gid * 3 + 2] = c2;
    int vx = b * R3 + ((int)rintf(c0) * 1024 + (int)rintf(c1) * 32 + (int)rintf(c2));
    atomicAdd(&cursor[vx], 1);
}

// scan stage 1: 256 blocks x 512 bins -> local exclusive scan + block totals
__global__ void k_scan1(int* __restrict__ cur, int* __restrict__ aux) {
    __shared__ int sm[256];
    int t = threadIdx.x;
    int base = blockIdx.x * 512 + t * 2;
    int c0 = cur[base], c1 = cur[base + 1];
    int s = c0 + c1;
    sm[t] = s; __syncthreads();
    for (int off = 1; off < 256; off <<= 1) {
        int v = (t >= off) ? sm[t - off] : 0;
        __syncthreads();
        sm[t] += v;
        __syncthreads();
    }
    int ex = sm[t] - s;
    cur[base] = ex;
    cur[base + 1] = ex + c0;
    if (t == 255) aux[blockIdx.x] = sm[t];
}

// scan stage 2+3 fused: each block reduces aux[0..blk) locally, adds offset
__global__ void k_scan3(int* __restrict__ cur, const int* __restrict__ aux) {
    __shared__ int sm[256];
    int t = threadIdx.x;
    sm[t] = (t < blockIdx.x) ? aux[t] : 0;
    __syncthreads();
    for (int off = 128; off > 0; off >>= 1) {
        if (t < off) sm[t] += sm[t + off];
        __syncthreads();
    }
    int add = sm[0];
    int base = blockIdx.x * 512 + t * 2;
    cur[base] += add;
    cur[base + 1] += add;
}

// features [B][64][N] fp32 -> FT [B][N][64] bf16 (LDS transpose)
__global__ __launch_bounds__(256) void k_trans(const float* __restrict__ feats,
                                               unsigned short* __restrict__ ft) {
    __shared__ float lds[64][65];
    int b = blockIdx.x >> 10;
    int n0 = (blockIdx.x & 1023) << 6;
    int tid = threadIdx.x;
    int nl = tid & 63;
    #pragma unroll
    for (int it = 0; it < 16; it++) {
        int ch = it * 4 + (tid >> 6);
        lds[nl][ch] = feats[((size_t)(b * 64 + ch) << 16) + n0 + nl];
    }
    __syncthreads();
    int nn = tid >> 2;
    int ch0 = (tid & 3) << 4;
    size_t obase = (((size_t)(b << 16) + n0 + nn) << 6) + ch0;
    short8 v0, v1;
    #pragma unroll
    for (int j = 0; j < 8; j++) v0[j] = (short)f2b(lds[nn][ch0 + j]);
    #pragma unroll
    for (int j = 0; j < 8; j++) v1[j] = (short)f2b(lds[nn][ch0 + 8 + j]);
    *(short8*)(ft + obase) = v0;
    *(short8*)(ft + obase + 8) = v1;
}

// place point ids into voxel-sorted order
__global__ void k_place(const float* __restrict__ cb3, int* __restrict__ cursor,
                        unsigned short* __restrict__ order) {
    int gid = blockIdx.x * 256 + threadIdx.x;
    int b = gid >> 16;
    float c0 = cb3[gid * 3], c1 = cb3[gid * 3 + 1], c2 = cb3[gid * 3 + 2];
    int vx = b * R3 + ((int)rintf(c0) * 1024 + (int)rintf(c1) * 32 + (int)rintf(c2));
    int slot = atomicAdd(&cursor[vx], 1);
    order[slot] = (unsigned short)(gid & 65535);
}

// one wave per voxel, point-parallel: lane = (point-slot p, ch-group g).
__global__ __launch_bounds__(256) void k_gather(const int* __restrict__ cursor,
        const unsigned short* __restrict__ order, const unsigned short* __restrict__ ft,
        unsigned short* __restrict__ g0) {
    int tid = threadIdx.x;
    int lane = tid & 63;
    int vx = blockIdx.x * 4 + (tid >> 6);
    int e = cursor[vx];
    int s = (vx == 0) ? 0 : cursor[vx - 1];
    int cnt = e - s;
    int p = lane >> 3;      // point slot 0..7
    int g = lane & 7;       // channel group 0..7 (8 channels each)
    int bb = vx >> 15;
    float acc[8] = {0.f, 0.f, 0.f, 0.f, 0.f, 0.f, 0.f, 0.f};
    for (int base = s; base < e; base += 8) {
        int idx = base + p;
        if (idx < e) {
            int n = order[idx];
            const unsigned short* fp = ft + (((size_t)(bb << 16) + n) << 6) + (g << 3);
            short8 v = *(const short8*)fp;
            #pragma unroll
            for (int j = 0; j < 8; j++) acc[j] += b2f((unsigned short)v[j]);
        }
    }
    #pragma unroll
    for (int j = 0; j < 8; j++) {
        acc[j] += __shfl_xor(acc[j], 8, 64);
        acc[j] += __shfl_xor(acc[j], 16, 64);
        acc[j] += __shfl_xor(acc[j], 32, 64);
    }
    if (p == 0) {
        float inv = 1.0f / (float)max(cnt, 1);
        int col = vx >> 5, z = vx & 31;
        short8 o8;
        #pragma unroll
        for (int j = 0; j < 8; j++) o8[j] = (short)f2b(acc[j] * inv);
        *(short8*)(g0 + (size_t)col * 2048 + (g << 8) + z * 8) = o8;
    }
}

// MFMA implicit-GEMM 3^3 conv, 4 columns/block, 512 threads / 8 waves.
// wave = (cp, nh, kh). Flat 54-step K-loop, fully unrolled, with an EXPLICIT
// software pipeline enforced by sched_barrier(0) fences (R4 showed that without
// fences the scheduler folds prefetch buffers back to just-in-time loads):
//   - weight ring wbuf[4], issued 3 steps ahead (~250cyc cover for L2 latency)
//   - A double-buffer a0/a1buf[2], issued 1 step ahead (covers ~120cyc LDS lat)
//   - z-edge via address-select to a zeroed 16B LDS slot (no post-wait VALU;
//     same-address reads broadcast, no bank conflict)
// launch_bounds(512,2) caps VGPR at 128 -> 2 blocks/CU retained.
// Split-K partials reduced via LDS (staging buffer reused); kh==0 waves finalize.
__global__ __launch_bounds__(512, 2) void k_conv(const unsigned short* __restrict__ in,
        const unsigned short* __restrict__ w, const float* __restrict__ bias,
        const float* __restrict__ idF, float* __restrict__ outF,
        unsigned short* __restrict__ out, int zmaj) {
    __shared__ unsigned short sA[18 * 2048 + 32];   // 72KB staged + 16B zero slot @36864
    int tid = threadIdx.x;
    int lane = tid & 63;
    int wid = tid >> 6;        // 0..7
    int cp = wid & 1;          // column pair: y0+2cp, y0+2cp+1
    int nh = (wid >> 1) & 1;   // out-channel half
    int kh = wid >> 2;         // K-half
    int tile = blockIdx.x;     // 0..255
    int b = blockIdx.y;
    int x = tile >> 3;
    int y0 = (tile & 7) << 2;
    int t = tid & 255;
    int h = tid >> 8;          // half-block stages even/odd columns
    int sq = wid & 3;          // quarter-wave within the 256-group

    if (tid < 4) ((float*)sA)[18432 + tid] = 0.f;   // zero slot

    // weight base: layout [tap 27][ks 4][nh 2][lane 64][j 8]
    const unsigned short* wl = w + nh * 512 + kh * 2048 + lane * 8;
    short8 wbuf[4];
    // prologue: issue W[0..2] (overlaps A staging below)
    #pragma unroll
    for (int s = 0; s < 3; s++)
        wbuf[s] = *(const short8*)(wl + (s / 6) * 12288 + ((s % 6) / 2) * 4096 + (s & 1) * 1024);

    #pragma unroll 1
    for (int s2 = 0; s2 < 9; s2++) {
        int s = s2 * 2 + h;
        int gx = x + s / 6 - 1;
        int gy = y0 + s % 6 - 1;
        if ((unsigned)gx < 32u && (unsigned)gy < 32u) {
            const unsigned short* gsrc = in + (((size_t)b * 1024 + gx * 32 + gy) << 11)
                                            + ((size_t)t << 3);
            __builtin_amdgcn_global_load_lds(
                (const __attribute__((address_space(1))) unsigned int*)gsrc,
                (__attribute__((address_space(3))) unsigned int*)(sA + s * 2048 + (sq << 9)),
                16, 0, 0);
        } else {
            ((float4*)(sA + s * 2048))[t] = make_float4(0.f, 0.f, 0.f, 0.f);
        }
    }
    __syncthreads();

    f32x16 accA = {}, accB = {};
    int half = lane >> 5;
    int z = lane & 31;
    int abase = (half << 8) + kh * 1024;     // shorts within a staged column
    short8 a0buf[2], a1buf[2];
    {   // A[0]: step 0 = (c9=0, dzi=0, ksi=0); zz = z-1
        int zz = z - 1;
        bool zv = zz >= 0;
        int base = (cp * 2) * 2048 + abase;  // c9=0 -> s0 = cp*2
        int a0 = zv ? (base + zz * 8) : 36864;
        int a1 = zv ? (base + 2048 + zz * 8) : 36864;
        a0buf[0] = *(const short8*)(sA + a0);
        a1buf[0] = *(const short8*)(sA + a1);
    }
    #pragma unroll
    for (int s = 0; s < 54; s++) {
        if (s < 53) {           // issue A loads for step s+1
            int sn = s + 1;
            int c9 = sn / 6, dzi = (sn % 6) / 2;
            int zz = z + dzi - 1;
            bool zv = (unsigned)zz < 32u;
            int s0 = (c9 / 3) * 6 + (c9 % 3) + cp * 2;
            int base = s0 * 2048 + abase + (sn & 1) * 512;
            int a0 = zv ? (base + zz * 8) : 36864;
            int a1 = zv ? (base + 2048 + zz * 8) : 36864;
            a0buf[sn & 1] = *(const short8*)(sA + a0);
            a1buf[sn & 1] = *(const short8*)(sA + a1);
        }
        if (s < 51) {           // issue W load for step s+3
            int sw = s + 3;
            wbuf[sw & 3] = *(const short8*)(wl + (sw / 6) * 12288
                                             + ((sw % 6) / 2) * 4096 + (sw & 1) * 1024);
        }
        __builtin_amdgcn_sched_barrier(0);   // loads stay above, MFMAs below
        accA = __builtin_amdgcn_mfma_f32_32x32x16_bf16(a0buf[s & 1], wbuf[s & 3], accA, 0, 0, 0);
        accB = __builtin_amdgcn_mfma_f32_32x32x16_bf16(a1buf[s & 1], wbuf[s & 3], accB, 0, 0, 0);
    }

    // split-K reduce across the kh wave pair, via LDS (reuse staging buffer)
    __syncthreads();
    float* RED = (float*)sA;
    if (kh == 1) {
        #pragma unroll
        for (int c = 0; c < 2; c++) {
            const f32x16& a = c ? accB : accA;
            #pragma unroll
            for (int rb = 0; rb < 4; rb++) {
                float4 v = make_float4(a[rb * 4], a[rb * 4 + 1], a[rb * 4 + 2], a[rb * 4 + 3]);
                ((float4*)(RED + ((((cp * 2 + nh) * 2 + c) * 4 + rb) << 8)))[lane] = v;
            }
        }
    }
    __syncthreads();
    if (kh == 0) {
        #pragma unroll
        for (int rb = 0; rb < 4; rb++) {
            float4 v0 = ((float4*)(RED + ((((cp * 2 + nh) * 2 + 0) * 4 + rb) << 8)))[lane];
            float4 v1 = ((float4*)(RED + ((((cp * 2 + nh) * 2 + 1) * 4 + rb) << 8)))[lane];
            accA[rb * 4]     += v0.x; accA[rb * 4 + 1] += v0.y;
            accA[rb * 4 + 2] += v0.z; accA[rb * 4 + 3] += v0.w;
            accB[rb * 4]     += v1.x; accB[rb * 4 + 1] += v1.y;
            accB[rb * 4 + 2] += v1.z; accB[rb * 4 + 3] += v1.w;
        }
        int o = nh * 32 + (lane & 31);
        float bb = bias[o];
        #pragma unroll
        for (int cc = 0; cc < 2; cc++) {
            int outcol = b * 1024 + x * 32 + (y0 + cp * 2 + cc);
            size_t cbase = (size_t)outcol << 11;
            size_t obase = cbase + (size_t)((o >> 3) << 8) + (o & 7);
            const f32x16& acc = cc ? accB : accA;
            #pragma unroll
            for (int r = 0; r < 16; r++) {
                int zr = (r & 3) + ((r >> 2) << 3) + ((lane >> 5) << 2);
                size_t oe = obase + (size_t)zr * 8;
                float v = acc[r] + bb;
                if (idF) v += idF[oe];
                v = fmaxf(v, 0.f);
                if (zmaj) out[cbase + (size_t)zr * 64 + o] = f2b(v);
                else out[oe] = f2b(v);
                if (outF) outF[oe] = v;
            }
        }
    }
}

// point-branch MLP via MFMA: pfeat[B][N][64] bf16 = relu(PW * feat + PB)
__global__ __launch_bounds__(256) void k_pfeat(const float* __restrict__ feats,
        const float* __restrict__ pb, const unsigned short* __restrict__ pwb,
        unsigned short* __restrict__ pf) {
    int tid = threadIdx.x;
    int lane = tid & 63;
    int wv = tid >> 6;
    int tile = blockIdx.x * 4 + wv;          // 0..8191
    int b = tile >> 11;
    int n0 = (tile & 2047) << 5;
    int m = lane & 31, kg = lane >> 5;
    const float* fb = feats + ((size_t)b << 22) + n0 + m;
    f32x16 acc0 = {}, acc1 = {};
    #pragma unroll
    for (int ks = 0; ks < 4; ks++) {
        short8 af;
        #pragma unroll
        for (int j = 0; j < 8; j++)
            af[j] = (short)f2b(fb[(size_t)(ks * 16 + kg * 8 + j) << 16]);
        short8 b0 = *(const short8*)(pwb + ((size_t)(ks * 64 + lane) << 3));
        short8 b1 = *(const short8*)(pwb + ((size_t)((4 + ks) * 64 + lane) << 3));
        acc0 = __builtin_amdgcn_mfma_f32_32x32x16_bf16(af, b0, acc0, 0, 0, 0);
        acc1 = __builtin_amdgcn_mfma_f32_32x32x16_bf16(af, b1, acc1, 0, 0, 0);
    }
    int och = lane & 31;
    float bias0 = pb[och], bias1 = pb[32 + och];
    #pragma unroll
    for (int r = 0; r < 16; r++) {
        int p = (r & 3) + ((r >> 2) << 3) + ((lane >> 5) << 2);
        size_t base = ((size_t)(b << 16) + n0 + p) << 6;
        pf[base + och]      = f2b(fmaxf(acc0[r] + bias0, 0.f));
        pf[base + 32 + och] = f2b(fmaxf(acc1[r] + bias1, 0.f));
    }
}

// devox gather (z-major grid) + pfeat load + collapsed attention + fuse.
// wave = 8 points x 8 channel-groups; per-corner loads coalesce to 8x128B segments.
__global__ __launch_bounds__(256) void k_final(const float* __restrict__ cb3,
        const unsigned short* __restrict__ gb, const unsigned short* __restrict__ pfeat,
        const float* __restrict__ ws, float* __restrict__ out) {
    int tid = threadIdx.x;
    int lane = tid & 63;
    int g = lane >> 3;      // channel group 0..7
    int p = lane & 7;       // point within wave
    int b = blockIdx.y;
    int n = (blockIdx.x << 5) + ((tid >> 6) << 3) + p;
    int gid = (b << 16) + n;
    float c0 = cb3[gid * 3], c1 = cb3[gid * 3 + 1], c2 = cb3[gid * 3 + 2];
    int lx = (int)floorf(c0), ly = (int)floorf(c1), lz = (int)floorf(c2);
    int hx = min(lx + 1, 31), hy = min(ly + 1, 31), hz = min(lz + 1, 31);
    float fx = c0 - (float)lx, fy = c1 - (float)ly, fz = c2 - (float)lz;
    int xs[2] = {lx, hx}; float wxx[2] = {1.f - fx, fx};
    int ys[2] = {ly, hy}; float wyy[2] = {1.f - fy, fy};
    int zs[2] = {lz, hz}; float wzz[2] = {1.f - fz, fz};
    float vf[8];
    #pragma unroll
    for (int j = 0; j < 8; j++) vf[j] = 0.f;
    #pragma unroll
    for (int ii = 0; ii < 2; ii++)
    #pragma unroll
    for (int jj = 0; jj < 2; jj++)
    #pragma unroll
    for (int kk = 0; kk < 2; kk++) {
        float wgt = wxx[ii] * wyy[jj] * wzz[kk];
        const unsigned short* gp = gb + (((size_t)b * 1024 + xs[ii] * 32 + ys[jj]) << 11)
                                      + zs[kk] * 64 + (g << 3);
        short8 v = *(const short8*)gp;
        #pragma unroll
        for (int j = 0; j < 8; j++) vf[j] += wgt * b2f((unsigned short)v[j]);
    }
    float pfv[8];
    const unsigned short* pp = pfeat + ((size_t)gid << 6) + (g << 3);
    short8 pv = *(const short8*)pp;
    #pragma unroll
    for (int j = 0; j < 8; j++) pfv[j] = b2f((unsigned short)pv[j]);
    const float* wae = ws + OFF_WAE + (g << 3);
    const float* wbe = ws + OFF_WBE + (g << 3);
    float part = 0.f;
    #pragma unroll
    for (int j = 0; j < 8; j++) part += wae[j] * vf[j] + wbe[j] * pfv[j];
    part += __shfl_xor(part, 8, 64);
    part += __shfl_xor(part, 16, 64);
    part += __shfl_xor(part, 32, 64);
    float q = part + ws[OFF_Q0];
    float attn = 1.0f + 1.0f / (1.0f + expf(-q));
    float* op = out + (((size_t)(b * 64 + (g << 3))) << 16) + n;
    #pragma unroll
    for (int j = 0; j < 8; j++) op[(size_t)j << 16] = vf[j] * attn + pfv[j];
}

extern "C" void kernel_launch(void* const* d_in, const int* in_sizes, int n_in,
                              void* d_out, int out_size, void* d_ws, size_t ws_size,
                              hipStream_t stream) {
    const float* features = (const float*)d_in[0];
    const float* coords   = (const float*)d_in[1];
    const float* vconv_w  = (const float*)d_in[2];
    const float* vconv_b  = (const float*)d_in[3];
    const float* vbn_g    = (const float*)d_in[4];
    const float* vbn_b    = (const float*)d_in[5];
    const float* res_w    = (const float*)d_in[6];
    const float* res_b    = (const float*)d_in[7];
    const float* res_bn_g = (const float*)d_in[8];
    const float* res_bn_b = (const float*)d_in[9];
    const float* pf_w     = (const float*)d_in[10];
    const float* pf_b     = (const float*)d_in[11];
    const float* pf_bn_g  = (const float*)d_in[12];
    const float* pf_bn_b  = (const float*)d_in[13];
    const float* attn_wa  = (const float*)d_in[14];
    const float* attn_ba  = (const float*)d_in[15];
    const float* attn_wb  = (const float*)d_in[16];
    const float* attn_bb  = (const float*)d_in[17];
    const float* attn_wc  = (const float*)d_in[18];
    const float* attn_bc  = (const float*)d_in[19];
    float* ws  = (float*)d_ws;
    float* out = (float*)d_out;

    unsigned short* WB  = (unsigned short*)(ws + OFF_WB16);
    unsigned short* PWB = (unsigned short*)(ws + OFF_PWB);
    int*            CUR = (int*)(ws + OFF_CUR);
    int*            AUX = (int*)(ws + OFF_AUX);
    unsigned short* ORD = (unsigned short*)(ws + OFF_ORD);
    unsigned short* FT  = (unsigned short*)(ws + OFF_GA);   // pre-conv overlay
    unsigned short* PF  = (unsigned short*)(ws + OFF_GA);   // post-conv overlay
    float* GA = ws + OFF_GA;
    unsigned short* G0 = (unsigned short*)(ws + OFF_G0);
    unsigned short* G1 = (unsigned short*)(ws + OFF_G1);
    const float* Bv = ws + OFF_BEFF;

    k_setup<<<2179, 256, 0, stream>>>(vconv_w, vconv_b, vbn_g, vbn_b, res_w, res_b,
                                      res_bn_g, res_bn_b, pf_w, pf_b, pf_bn_g, pf_bn_b,
                                      attn_wa, attn_ba, attn_wb, attn_bb, attn_wc, attn_bc, ws);
    k_mean1<<<96, 256, 0, stream>>>(coords, ws + OFF_PART, (float4*)CUR);
    k_maxn1<<<32, 256, 0, stream>>>(coords, ws + OFF_PART, ws + OFF_MEAN);
    k_prep<<<1024, 256, 0, stream>>>(coords, ws + OFF_MEAN, ws + OFF_PART,
                                     ws + OFF_CB3, CUR);
    k_scan1<<<256, 256, 0, stream>>>(CUR, AUX);
    k_scan3<<<256, 256, 0, stream>>>(CUR, AUX);
    k_trans<<<4096, 256, 0, stream>>>(features, FT);
    k_place<<<1024, 256, 0, stream>>>(ws + OFF_CB3, CUR, ORD);
    k_gather<<<32768, 256, 0, stream>>>(CUR, ORD, FT, G0);

    dim3 cg(256, 4);
    k_conv<<<cg, 512, 0, stream>>>(G0, WB + 0 * 110592, Bv + 0,   nullptr, GA,      G1, 0);
    k_conv<<<cg, 512, 0, stream>>>(G1, WB + 1 * 110592, Bv + 64,  nullptr, nullptr, G0, 0);
    k_conv<<<cg, 512, 0, stream>>>(G0, WB + 2 * 110592, Bv + 128, GA,      GA,      G1, 0);
    k_conv<<<cg, 512, 0, stream>>>(G1, WB + 3 * 110592, Bv + 192, nullptr, nullptr, G0, 0);
    k_conv<<<cg, 512, 0, stream>>>(G0, WB + 4 * 110592, Bv + 256, GA,      nullptr, G1, 1);

    k_pfeat<<<2048, 256, 0, stream>>>(features, ws + OFF_PB, PWB, PF);

    dim3 fg(2048, 4);
    k_final<<<fg, 256, 0, stream>>>(ws + OFF_CB3, G1, PF, ws, out);
}

// Round 6
// 481.012 us; speedup vs baseline: 1.1096x; 1.0698x over previous
//
#include <hip/hip_runtime.h>
#include <math.h>

#define NPT 65536
#define NB 4
#define R3 32768

typedef __attribute__((ext_vector_type(8))) short short8;
typedef __attribute__((ext_vector_type(16))) float f32x16;

// ws layout (float offsets)
#define OFF_WB16 0          // 276480 floats = 552960 bf16: 5 conv layers, B-frag order
#define OFF_BEFF 276480     // 5*64 conv biases (BN-folded)
#define OFF_PWB  276800     // 2048 floats = 4096 bf16: point-branch weights, B-frag order
#define OFF_PB   280896     // 64
#define OFF_WAE  280960     // 64
#define OFF_WBE  281024     // 64
#define OFF_Q0   281088     // 1 (+pad)
#define OFF_MEAN 281104     // 12
#define OFF_MAXN 281116     // 4
#define OFF_PART 281120     // 128 reduction partials (96 mean + 32 max)
#define OFF_AUX  281248     // 256 scan block sums (int)
#define OFF_CB3  281504     // 786432: 3 floats/point normalized coords
#define OFF_CUR  1067936    // 131072 int cursor
#define OFF_ORD  1199008    // 131072 floats = 262144 ushort sorted point ids
#define OFF_GA   1330080    // 8388608 fp32 residual; FT bf16 overlays pre-conv; PF bf16 overlays post-conv
#define OFF_G0   9718688    // 4194304 floats = 8388608 bf16 swizzled grid ping
#define OFF_G1   13912992   // 4194304 floats = 8388608 bf16 swizzled grid pong

__device__ __forceinline__ unsigned short f2b(float f) {
    union { float f; unsigned int u; } v; v.f = f;
    unsigned int r = v.u + 0x7fffu + ((v.u >> 16) & 1u);
    return (unsigned short)(r >> 16);
}
__device__ __forceinline__ float b2f(unsigned short u) {
    union { unsigned int u; float f; } v; v.u = ((unsigned int)u) << 16; return v.f;
}

// merged: conv-weight fold (idx < 552960) + misc param prep (idx >= 552960)
// conv weight layout (per layer, shorts): [tap 27][ks 4][nh 2][lane 64][j 8]
__global__ void k_setup(const float* __restrict__ vconv_w, const float* __restrict__ vconv_b,
                        const float* __restrict__ vbn_g, const float* __restrict__ vbn_b,
                        const float* __restrict__ res_w, const float* __restrict__ res_b,
                        const float* __restrict__ res_bn_g, const float* __restrict__ res_bn_b,
                        const float* __restrict__ pf_w, const float* __restrict__ pf_b,
                        const float* __restrict__ pf_bn_g, const float* __restrict__ pf_bn_b,
                        const float* __restrict__ wa, const float* __restrict__ ba,
                        const float* __restrict__ wb, const float* __restrict__ bb,
                        const float* __restrict__ wc, const float* __restrict__ bc,
                        float* __restrict__ ws) {
    int idx = blockIdx.x * 256 + threadIdx.x;
    const float invs = rsqrtf(1.00001f);
    if (idx < 552960) {
        unsigned short* wb16 = (unsigned short*)(ws + OFF_WB16);
        int j = idx & 7;
        int l = (idx >> 3) & 63;
        int nh = (idx >> 9) & 1;
        int ks = (idx >> 10) & 3;
        int rest = idx >> 12;          // layer*27 + t
        int t = rest % 27;
        int layer = rest / 27;
        int i = ks * 16 + ((l >> 5) << 3) + j;
        int o = nh * 32 + (l & 31);
        float scale, wsrc;
        if (layer == 0) {
            scale = vbn_g[o] * invs;
            wsrc = vconv_w[(o * 64 + i) * 27 + t];
        } else {
            scale = res_bn_g[(layer - 1) * 64 + o] * invs;
            wsrc = res_w[(size_t)(layer - 1) * 110592 + (o * 64 + i) * 27 + t];
        }
        wb16[idx] = f2b(wsrc * scale);
        return;
    }
    idx -= 552960;
    if (idx < 320) {
        int l = idx >> 6, o = idx & 63;
        float b_, g_, s_;
        if (l == 0) { b_ = vconv_b[o]; g_ = vbn_g[o]; s_ = vbn_b[o]; }
        else {
            b_ = res_b[(l - 1) * 64 + o];
            g_ = res_bn_g[(l - 1) * 64 + o];
            s_ = res_bn_b[(l - 1) * 64 + o];
        }
        ws[OFF_BEFF + idx] = b_ * g_ * invs + s_;
    } else if (idx < 4416) {
        int e = idx - 320;                 // 0..4095
        int j = e & 7;
        int lane = (e >> 3) & 63;
        int ks = (e >> 9) & 3;
        int half = e >> 11;
        int i = ks * 16 + ((lane >> 5) << 3) + j;
        int o = half * 32 + (lane & 31);
        ((unsigned short*)(ws + OFF_PWB))[e] = f2b(pf_w[o * 64 + i] * pf_bn_g[o] * invs);
    } else if (idx < 4480) {
        int o = idx - 4416;
        ws[OFF_PB + o] = pf_b[o] * pf_bn_g[o] * invs + pf_bn_b[o];
    } else if (idx < 4544) {
        int o = idx - 4480;
        float s = 0.f;
        for (int j = 0; j < 16; j++) s += wc[j] * wa[j * 64 + o];
        ws[OFF_WAE + o] = s;
    } else if (idx < 4608) {
        int o = idx - 4544;
        float s = 0.f;
        for (int j = 0; j < 16; j++) s += wc[16 + j] * wb[j * 64 + o];
        ws[OFF_WBE + o] = s;
    } else if (idx == 4608) {
        float s = bc[0];
        for (int j = 0; j < 16; j++) s += wc[j] * ba[j] + wc[16 + j] * bb[j];
        ws[OFF_Q0] = s;
    }
}

// stage-1 mean partials (96 blocks = 12 (b,d) x 8 chunks) + grid-stride zero of CUR
__global__ __launch_bounds__(256) void k_mean1(const float* __restrict__ coords,
                                               float* __restrict__ part,
                                               float4* __restrict__ curz) {
    for (int i = blockIdx.x * 256 + threadIdx.x; i < 32768; i += 96 * 256)
        curz[i] = make_float4(0.f, 0.f, 0.f, 0.f);
    __shared__ float sm[256];
    int bd = blockIdx.x >> 3, chunk = blockIdx.x & 7;
    int tid = threadIdx.x;
    const float* p = coords + (size_t)bd * NPT + chunk * 8192;
    float s = 0.f;
    for (int n = tid; n < 8192; n += 256) s += p[n];
    sm[tid] = s; __syncthreads();
    for (int st = 128; st > 0; st >>= 1) {
        if (tid < st) sm[tid] += sm[tid + st];
        __syncthreads();
    }
    if (tid == 0) part[blockIdx.x] = sm[0];
}

// stage-1 max-norm^2 partials (32 blocks = 4 b x 8 chunks); mean computed from partials inline.
// chunk-0 block stores mean for k_prep.
__global__ __launch_bounds__(256) void k_maxn1(const float* __restrict__ coords,
                                               float* __restrict__ part,
                                               float* __restrict__ mean) {
    __shared__ float sm[256];
    int b = blockIdx.x >> 3, chunk = blockIdx.x & 7;
    int tid = threadIdx.x;
    float m0 = 0.f, m1 = 0.f, m2 = 0.f;
    #pragma unroll
    for (int c = 0; c < 8; c++) {
        m0 += part[(b * 3 + 0) * 8 + c];
        m1 += part[(b * 3 + 1) * 8 + c];
        m2 += part[(b * 3 + 2) * 8 + c];
    }
    m0 *= (1.0f / NPT); m1 *= (1.0f / NPT); m2 *= (1.0f / NPT);
    if (chunk == 0 && tid == 0) {
        mean[b * 3] = m0; mean[b * 3 + 1] = m1; mean[b * 3 + 2] = m2;
    }
    const float* p0 = coords + (size_t)(b * 3) * NPT + chunk * 8192;
    float mx = 0.f;
    for (int n = tid; n < 8192; n += 256) {
        float dx = p0[n] - m0, dy = p0[NPT + n] - m1, dz = p0[2 * NPT + n] - m2;
        mx = fmaxf(mx, dx * dx + dy * dy + dz * dz);
    }
    sm[tid] = mx; __syncthreads();
    for (int st = 128; st > 0; st >>= 1) {
        if (tid < st) sm[tid] = fmaxf(sm[tid], sm[tid + st]);
        __syncthreads();
    }
    if (tid == 0) part[96 + blockIdx.x] = sm[0];
}

// per-point normalized coords + voxel histogram; max-norm finalized inline from partials
__global__ void k_prep(const float* __restrict__ coords, const float* __restrict__ mean,
                       const float* __restrict__ part, float* __restrict__ cb3,
                       int* __restrict__ cursor) {
    int gid = blockIdx.x * 256 + threadIdx.x;
    int b = gid >> 16, n = gid & 65535;
    float mx = 0.f;
    #pragma unroll
    for (int c = 0; c < 8; c++) mx = fmaxf(mx, part[96 + b * 8 + c]);
    float inv = 0.5f / sqrtf(mx);
    float c0 = (coords[(size_t)(b * 3) * NPT + n]     - mean[b * 3])     * inv + 0.5f;
    float c1 = (coords[(size_t)(b * 3 + 1) * NPT + n] - mean[b * 3 + 1]) * inv + 0.5f;
    float c2 = (coords[(size_t)(b * 3 + 2) * NPT + n] - mean[b * 3 + 2]) * inv + 0.5f;
    c0 = fminf(fmaxf(c0 * 32.f, 0.f), 31.f);
    c1 = fminf(fmaxf(c1 * 32.f, 0.f), 31.f);
    c2 = fminf(fmaxf(c2 * 32.f, 0.f), 31.f);
    cb3[gid * 3]     = c0;
    cb3[gid * 3 + 1] = c1;
    cb3[gid * 3 + 2] = c2;
    int vx = b * R3 + ((int)rintf(c0) * 1024 + (int)rintf(c1) * 32 + (int)rintf(c2));
    atomicAdd(&cursor[vx], 1);
}

// scan stage 1: 256 blocks x 512 bins -> local exclusive scan + block totals
__global__ void k_scan1(int* __restrict__ cur, int* __restrict__ aux) {
    __shared__ int sm[256];
    int t = threadIdx.x;
    int base = blockIdx.x * 512 + t * 2;
    int c0 = cur[base], c1 = cur[base + 1];
    int s = c0 + c1;
    sm[t] = s; __syncthreads();
    for (int off = 1; off < 256; off <<= 1) {
        int v = (t >= off) ? sm[t - off] : 0;
        __syncthreads();
        sm[t] += v;
        __syncthreads();
    }
    int ex = sm[t] - s;
    cur[base] = ex;
    cur[base + 1] = ex + c0;
    if (t == 255) aux[blockIdx.x] = sm[t];
}

// scan stage 2+3 fused: each block reduces aux[0..blk) locally, adds offset
__global__ void k_scan3(int* __restrict__ cur, const int* __restrict__ aux) {
    __shared__ int sm[256];
    int t = threadIdx.x;
    sm[t] = (t < blockIdx.x) ? aux[t] : 0;
    __syncthreads();
    for (int off = 128; off > 0; off >>= 1) {
        if (t < off) sm[t] += sm[t + off];
        __syncthreads();
    }
    int add = sm[0];
    int base = blockIdx.x * 512 + t * 2;
    cur[base] += add;
    cur[base + 1] += add;
}

// features [B][64][N] fp32 -> FT [B][N][64] bf16 (LDS transpose)
__global__ __launch_bounds__(256) void k_trans(const float* __restrict__ feats,
                                               unsigned short* __restrict__ ft) {
    __shared__ float lds[64][65];
    int b = blockIdx.x >> 10;
    int n0 = (blockIdx.x & 1023) << 6;
    int tid = threadIdx.x;
    int nl = tid & 63;
    #pragma unroll
    for (int it = 0; it < 16; it++) {
        int ch = it * 4 + (tid >> 6);
        lds[nl][ch] = feats[((size_t)(b * 64 + ch) << 16) + n0 + nl];
    }
    __syncthreads();
    int nn = tid >> 2;
    int ch0 = (tid & 3) << 4;
    size_t obase = (((size_t)(b << 16) + n0 + nn) << 6) + ch0;
    short8 v0, v1;
    #pragma unroll
    for (int j = 0; j < 8; j++) v0[j] = (short)f2b(lds[nn][ch0 + j]);
    #pragma unroll
    for (int j = 0; j < 8; j++) v1[j] = (short)f2b(lds[nn][ch0 + 8 + j]);
    *(short8*)(ft + obase) = v0;
    *(short8*)(ft + obase + 8) = v1;
}

// place point ids into voxel-sorted order
__global__ void k_place(const float* __restrict__ cb3, int* __restrict__ cursor,
                        unsigned short* __restrict__ order) {
    int gid = blockIdx.x * 256 + threadIdx.x;
    int b = gid >> 16;
    float c0 = cb3[gid * 3], c1 = cb3[gid * 3 + 1], c2 = cb3[gid * 3 + 2];
    int vx = b * R3 + ((int)rintf(c0) * 1024 + (int)rintf(c1) * 32 + (int)rintf(c2));
    int slot = atomicAdd(&cursor[vx], 1);
    order[slot] = (unsigned short)(gid & 65535);
}

// one wave per voxel, point-parallel: lane = (point-slot p, ch-group g).
__global__ __launch_bounds__(256) void k_gather(const int* __restrict__ cursor,
        const unsigned short* __restrict__ order, const unsigned short* __restrict__ ft,
        unsigned short* __restrict__ g0) {
    int tid = threadIdx.x;
    int lane = tid & 63;
    int vx = blockIdx.x * 4 + (tid >> 6);
    int e = cursor[vx];
    int s = (vx == 0) ? 0 : cursor[vx - 1];
    int cnt = e - s;
    int p = lane >> 3;      // point slot 0..7
    int g = lane & 7;       // channel group 0..7 (8 channels each)
    int bb = vx >> 15;
    float acc[8] = {0.f, 0.f, 0.f, 0.f, 0.f, 0.f, 0.f, 0.f};
    for (int base = s; base < e; base += 8) {
        int idx = base + p;
        if (idx < e) {
            int n = order[idx];
            const unsigned short* fp = ft + (((size_t)(bb << 16) + n) << 6) + (g << 3);
            short8 v = *(const short8*)fp;
            #pragma unroll
            for (int j = 0; j < 8; j++) acc[j] += b2f((unsigned short)v[j]);
        }
    }
    #pragma unroll
    for (int j = 0; j < 8; j++) {
        acc[j] += __shfl_xor(acc[j], 8, 64);
        acc[j] += __shfl_xor(acc[j], 16, 64);
        acc[j] += __shfl_xor(acc[j], 32, 64);
    }
    if (p == 0) {
        float inv = 1.0f / (float)max(cnt, 1);
        int col = vx >> 5, z = vx & 31;
        short8 o8;
        #pragma unroll
        for (int j = 0; j < 8; j++) o8[j] = (short)f2b(acc[j] * inv);
        *(short8*)(g0 + (size_t)col * 2048 + (g << 8) + z * 8) = o8;
    }
}

// MFMA implicit-GEMM 3^3 conv, 4 columns/block, 512 threads / 8 waves.
// wave = (cp, nh, kh). R5 pipelined MFMA loop (sched_barrier fences, W ring depth 3,
// A double-buffer, z-edge via zeroed-LDS address select) + NEW coalesced epilogue:
// all waves dump fp32 accs into a stride-65 LDS buffer (conflict-free both ways),
// then 512 threads read back split-K-summed values in OUTPUT order and do full
// b128 bf16 stores / dwordx4 fp32 stores / dwordx4 idF loads. R5's 2-byte scatter
// stores caused 3x HBM write amplification (WRITE_SIZE 49MB for 16MB of output)
// plus write-allocate RMW fetches - that was the serial per-block tail.
__global__ __launch_bounds__(512, 2) void k_conv(const unsigned short* __restrict__ in,
        const unsigned short* __restrict__ w, const float* __restrict__ bias,
        const float* __restrict__ idF, float* __restrict__ outF,
        unsigned short* __restrict__ out, int zmaj) {
    __shared__ unsigned short sA[18 * 2048 + 32];   // 72KB staged + 16B zero slot @36864
    int tid = threadIdx.x;
    int lane = tid & 63;
    int wid = tid >> 6;        // 0..7
    int cp = wid & 1;          // column pair: y0+2cp, y0+2cp+1
    int nh = (wid >> 1) & 1;   // out-channel half
    int kh = wid >> 2;         // K-half
    int tile = blockIdx.x;     // 0..255
    int b = blockIdx.y;
    int x = tile >> 3;
    int y0 = (tile & 7) << 2;
    int t = tid & 255;
    int h = tid >> 8;          // half-block stages even/odd columns
    int sq = wid & 3;          // quarter-wave within the 256-group

    if (tid < 4) ((float*)sA)[18432 + tid] = 0.f;   // zero slot

    // weight base: layout [tap 27][ks 4][nh 2][lane 64][j 8]
    const unsigned short* wl = w + nh * 512 + kh * 2048 + lane * 8;
    short8 wbuf[4];
    // prologue: issue W[0..2] (overlaps A staging below)
    #pragma unroll
    for (int s = 0; s < 3; s++)
        wbuf[s] = *(const short8*)(wl + (s / 6) * 12288 + ((s % 6) / 2) * 4096 + (s & 1) * 1024);

    #pragma unroll 1
    for (int s2 = 0; s2 < 9; s2++) {
        int s = s2 * 2 + h;
        int gx = x + s / 6 - 1;
        int gy = y0 + s % 6 - 1;
        if ((unsigned)gx < 32u && (unsigned)gy < 32u) {
            const unsigned short* gsrc = in + (((size_t)b * 1024 + gx * 32 + gy) << 11)
                                            + ((size_t)t << 3);
            __builtin_amdgcn_global_load_lds(
                (const __attribute__((address_space(1))) unsigned int*)gsrc,
                (__attribute__((address_space(3))) unsigned int*)(sA + s * 2048 + (sq << 9)),
                16, 0, 0);
        } else {
            ((float4*)(sA + s * 2048))[t] = make_float4(0.f, 0.f, 0.f, 0.f);
        }
    }
    __syncthreads();

    f32x16 accA = {}, accB = {};
    int half = lane >> 5;
    int z = lane & 31;
    int abase = (half << 8) + kh * 1024;     // shorts within a staged column
    short8 a0buf[2], a1buf[2];
    {   // A[0]: step 0 = (c9=0, dzi=0, ksi=0); zz = z-1
        int zz = z - 1;
        bool zv = zz >= 0;
        int base = (cp * 2) * 2048 + abase;  // c9=0 -> s0 = cp*2
        int a0 = zv ? (base + zz * 8) : 36864;
        int a1 = zv ? (base + 2048 + zz * 8) : 36864;
        a0buf[0] = *(const short8*)(sA + a0);
        a1buf[0] = *(const short8*)(sA + a1);
    }
    #pragma unroll
    for (int s = 0; s < 54; s++) {
        if (s < 53) {           // issue A loads for step s+1
            int sn = s + 1;
            int c9 = sn / 6, dzi = (sn % 6) / 2;
            int zz = z + dzi - 1;
            bool zv = (unsigned)zz < 32u;
            int s0 = (c9 / 3) * 6 + (c9 % 3) + cp * 2;
            int base = s0 * 2048 + abase + (sn & 1) * 512;
            int a0 = zv ? (base + zz * 8) : 36864;
            int a1 = zv ? (base + 2048 + zz * 8) : 36864;
            a0buf[sn & 1] = *(const short8*)(sA + a0);
            a1buf[sn & 1] = *(const short8*)(sA + a1);
        }
        if (s < 51) {           // issue W load for step s+3
            int sw = s + 3;
            wbuf[sw & 3] = *(const short8*)(wl + (sw / 6) * 12288
                                             + ((sw % 6) / 2) * 4096 + (sw & 1) * 1024);
        }
        __builtin_amdgcn_sched_barrier(0);   // loads stay above, MFMAs below
        accA = __builtin_amdgcn_mfma_f32_32x32x16_bf16(a0buf[s & 1], wbuf[s & 3], accA, 0, 0, 0);
        accB = __builtin_amdgcn_mfma_f32_32x32x16_bf16(a1buf[s & 1], wbuf[s & 3], accB, 0, 0, 0);
    }

    // ---- coalesced epilogue: dump accs to LDS (stride-65 rows), then coalesced readout
    __syncthreads();                          // staging buffer no longer needed
    float* RED = (float*)sA;                  // [kh 2][col 4][zr 32] rows of 65 floats
    int o = nh * 32 + (lane & 31);
    #pragma unroll
    for (int cc = 0; cc < 2; cc++) {
        const f32x16& acc = cc ? accB : accA;
        int col = cp * 2 + cc;
        #pragma unroll
        for (int r = 0; r < 16; r++) {
            int zr = (r & 3) + ((r >> 2) << 3) + ((lane >> 5) << 2);
            RED[((kh * 4 + col) * 32 + zr) * 65 + o] = acc[r];
        }
    }
    __syncthreads();
    #pragma unroll
    for (int e = 0; e < 2; e++) {
        int idx = e * 512 + tid;              // 0..1023 output groups of 8ch
        int col = idx >> 8;                   // 0..3
        int g = (idx >> 5) & 7;               // channel group
        int z2 = idx & 31;                    // z
        const float* r0 = RED + ((0 * 4 + col) * 32 + z2) * 65 + g * 8;
        const float* r1 = RED + ((1 * 4 + col) * 32 + z2) * 65 + g * 8;
        int outcol = b * 1024 + x * 32 + y0 + col;
        size_t cbase = (size_t)outcol << 11;          // short index of column base
        size_t swz = cbase + g * 256 + z2 * 8;        // swizzled short index
        float vv[8];
        #pragma unroll
        for (int j = 0; j < 8; j++) vv[j] = r0[j] + r1[j] + bias[g * 8 + j];
        if (idF) {
            #pragma unroll
            for (int j = 0; j < 8; j++) vv[j] += idF[swz + j];
        }
        #pragma unroll
        for (int j = 0; j < 8; j++) vv[j] = fmaxf(vv[j], 0.f);
        short8 o8;
        #pragma unroll
        for (int j = 0; j < 8; j++) o8[j] = (short)f2b(vv[j]);
        if (zmaj) *(short8*)(out + cbase + z2 * 64 + g * 8) = o8;
        else      *(short8*)(out + swz) = o8;
        if (outF) {
            #pragma unroll
            for (int j = 0; j < 8; j++) outF[swz + j] = vv[j];
        }
    }
}

// point-branch MLP via MFMA: pfeat[B][N][64] bf16 = relu(PW * feat + PB)
__global__ __launch_bounds__(256) void k_pfeat(const float* __restrict__ feats,
        const float* __restrict__ pb, const unsigned short* __restrict__ pwb,
        unsigned short* __restrict__ pf) {
    int tid = threadIdx.x;
    int lane = tid & 63;
    int wv = tid >> 6;
    int tile = blockIdx.x * 4 + wv;          // 0..8191
    int b = tile >> 11;
    int n0 = (tile & 2047) << 5;
    int m = lane & 31, kg = lane >> 5;
    const float* fb = feats + ((size_t)b << 22) + n0 + m;
    f32x16 acc0 = {}, acc1 = {};
    #pragma unroll
    for (int ks = 0; ks < 4; ks++) {
        short8 af;
        #pragma unroll
        for (int j = 0; j < 8; j++)
            af[j] = (short)f2b(fb[(size_t)(ks * 16 + kg * 8 + j) << 16]);
        short8 b0 = *(const short8*)(pwb + ((size_t)(ks * 64 + lane) << 3));
        short8 b1 = *(const short8*)(pwb + ((size_t)((4 + ks) * 64 + lane) << 3));
        acc0 = __builtin_amdgcn_mfma_f32_32x32x16_bf16(af, b0, acc0, 0, 0, 0);
        acc1 = __builtin_amdgcn_mfma_f32_32x32x16_bf16(af, b1, acc1, 0, 0, 0);
    }
    int och = lane & 31;
    float bias0 = pb[och], bias1 = pb[32 + och];
    #pragma unroll
    for (int r = 0; r < 16; r++) {
        int p = (r & 3) + ((r >> 2) << 3) + ((lane >> 5) << 2);
        size_t base = ((size_t)(b << 16) + n0 + p) << 6;
        pf[base + och]      = f2b(fmaxf(acc0[r] + bias0, 0.f));
        pf[base + 32 + och] = f2b(fmaxf(acc1[r] + bias1, 0.f));
    }
}

// devox gather (z-major grid) + pfeat load + collapsed attention + fuse.
// wave = 8 points x 8 channel-groups; per-corner loads coalesce to 8x128B segments.
__global__ __launch_bounds__(256) void k_final(const float* __restrict__ cb3,
        const unsigned short* __restrict__ gb, const unsigned short* __restrict__ pfeat,
        const float* __restrict__ ws, float* __restrict__ out) {
    int tid = threadIdx.x;
    int lane = tid & 63;
    int g = lane >> 3;      // channel group 0..7
    int p = lane & 7;       // point within wave
    int b = blockIdx.y;
    int n = (blockIdx.x << 5) + ((tid >> 6) << 3) + p;
    int gid = (b << 16) + n;
    float c0 = cb3[gid * 3], c1 = cb3[gid * 3 + 1], c2 = cb3[gid * 3 + 2];
    int lx = (int)floorf(c0), ly = (int)floorf(c1), lz = (int)floorf(c2);
    int hx = min(lx + 1, 31), hy = min(ly + 1, 31), hz = min(lz + 1, 31);
    float fx = c0 - (float)lx, fy = c1 - (float)ly, fz = c2 - (float)lz;
    int xs[2] = {lx, hx}; float wxx[2] = {1.f - fx, fx};
    int ys[2] = {ly, hy}; float wyy[2] = {1.f - fy, fy};
    int zs[2] = {lz, hz}; float wzz[2] = {1.f - fz, fz};
    float vf[8];
    #pragma unroll
    for (int j = 0; j < 8; j++) vf[j] = 0.f;
    #pragma unroll
    for (int ii = 0; ii < 2; ii++)
    #pragma unroll
    for (int jj = 0; jj < 2; jj++)
    #pragma unroll
    for (int kk = 0; kk < 2; kk++) {
        float wgt = wxx[ii] * wyy[jj] * wzz[kk];
        const unsigned short* gp = gb + (((size_t)b * 1024 + xs[ii] * 32 + ys[jj]) << 11)
                                      + zs[kk] * 64 + (g << 3);
        short8 v = *(const short8*)gp;
        #pragma unroll
        for (int j = 0; j < 8; j++) vf[j] += wgt * b2f((unsigned short)v[j]);
    }
    float pfv[8];
    const unsigned short* pp = pfeat + ((size_t)gid << 6) + (g << 3);
    short8 pv = *(const short8*)pp;
    #pragma unroll
    for (int j = 0; j < 8; j++) pfv[j] = b2f((unsigned short)pv[j]);
    const float* wae = ws + OFF_WAE + (g << 3);
    const float* wbe = ws + OFF_WBE + (g << 3);
    float part = 0.f;
    #pragma unroll
    for (int j = 0; j < 8; j++) part += wae[j] * vf[j] + wbe[j] * pfv[j];
    part += __shfl_xor(part, 8, 64);
    part += __shfl_xor(part, 16, 64);
    part += __shfl_xor(part, 32, 64);
    float q = part + ws[OFF_Q0];
    float attn = 1.0f + 1.0f / (1.0f + expf(-q));
    float* op = out + (((size_t)(b * 64 + (g << 3))) << 16) + n;
    #pragma unroll
    for (int j = 0; j < 8; j++) op[(size_t)j << 16] = vf[j] * attn + pfv[j];
}

extern "C" void kernel_launch(void* const* d_in, const int* in_sizes, int n_in,
                              void* d_out, int out_size, void* d_ws, size_t ws_size,
                              hipStream_t stream) {
    const float* features = (const float*)d_in[0];
    const float* coords   = (const float*)d_in[1];
    const float* vconv_w  = (const float*)d_in[2];
    const float* vconv_b  = (const float*)d_in[3];
    const float* vbn_g    = (const float*)d_in[4];
    const float* vbn_b    = (const float*)d_in[5];
    const float* res_w    = (const float*)d_in[6];
    const float* res_b    = (const float*)d_in[7];
    const float* res_bn_g = (const float*)d_in[8];
    const float* res_bn_b = (const float*)d_in[9];
    const float* pf_w     = (const float*)d_in[10];
    const float* pf_b     = (const float*)d_in[11];
    const float* pf_bn_g  = (const float*)d_in[12];
    const float* pf_bn_b  = (const float*)d_in[13];
    const float* attn_wa  = (const float*)d_in[14];
    const float* attn_ba  = (const float*)d_in[15];
    const float* attn_wb  = (const float*)d_in[16];
    const float* attn_bb  = (const float*)d_in[17];
    const float* attn_wc  = (const float*)d_in[18];
    const float* attn_bc  = (const float*)d_in[19];
    float* ws  = (float*)d_ws;
    float* out = (float*)d_out;

    unsigned short* WB  = (unsigned short*)(ws + OFF_WB16);
    unsigned short* PWB = (unsigned short*)(ws + OFF_PWB);
    int*            CUR = (int*)(ws + OFF_CUR);
    int*            AUX = (int*)(ws + OFF_AUX);
    unsigned short* ORD = (unsigned short*)(ws + OFF_ORD);
    unsigned short* FT  = (unsigned short*)(ws + OFF_GA);   // pre-conv overlay
    unsigned short* PF  = (unsigned short*)(ws + OFF_GA);   // post-conv overlay
    float* GA = ws + OFF_GA;
    unsigned short* G0 = (unsigned short*)(ws + OFF_G0);
    unsigned short* G1 = (unsigned short*)(ws + OFF_G1);
    const float* Bv = ws + OFF_BEFF;

    k_setup<<<2179, 256, 0, stream>>>(vconv_w, vconv_b, vbn_g, vbn_b, res_w, res_b,
                                      res_bn_g, res_bn_b, pf_w, pf_b, pf_bn_g, pf_bn_b,
                                      attn_wa, attn_ba, attn_wb, attn_bb, attn_wc, attn_bc, ws);
    k_mean1<<<96, 256, 0, stream>>>(coords, ws + OFF_PART, (float4*)CUR);
    k_maxn1<<<32, 256, 0, stream>>>(coords, ws + OFF_PART, ws + OFF_MEAN);
    k_prep<<<1024, 256, 0, stream>>>(coords, ws + OFF_MEAN, ws + OFF_PART,
                                     ws + OFF_CB3, CUR);
    k_scan1<<<256, 256, 0, stream>>>(CUR, AUX);
    k_scan3<<<256, 256, 0, stream>>>(CUR, AUX);
    k_trans<<<4096, 256, 0, stream>>>(features, FT);
    k_place<<<1024, 256, 0, stream>>>(ws + OFF_CB3, CUR, ORD);
    k_gather<<<32768, 256, 0, stream>>>(CUR, ORD, FT, G0);

    dim3 cg(256, 4);
    k_conv<<<cg, 512, 0, stream>>>(G0, WB + 0 * 110592, Bv + 0,   nullptr, GA,      G1, 0);
    k_conv<<<cg, 512, 0, stream>>>(G1, WB + 1 * 110592, Bv + 64,  nullptr, nullptr, G0, 0);
    k_conv<<<cg, 512, 0, stream>>>(G0, WB + 2 * 110592, Bv + 128, GA,      GA,      G1, 0);
    k_conv<<<cg, 512, 0, stream>>>(G1, WB + 3 * 110592, Bv + 192, nullptr, nullptr, G0, 0);
    k_conv<<<cg, 512, 0, stream>>>(G0, WB + 4 * 110592, Bv + 256, GA,      nullptr, G1, 1);

    k_pfeat<<<2048, 256, 0, stream>>>(features, ws + OFF_PB, PWB, PF);

    dim3 fg(2048, 4);
    k_final<<<fg, 256, 0, stream>>>(ws + OFF_CB3, G1, PF, ws, out);
}